// Round 1
// baseline (1997.647 us; speedup 1.0000x reference)
//
#include <hip/hip_runtime.h>
#include <math.h>

#define NN 100000
#define NE 1600000
#define F_IN 128
#define HEADS 4
#define HC 128
#define NEG_SLOPE 0.2f

// ---------------------------------------------------------------------------
// Kernel 0: detect int64 vs int32 edge_index. int64 little-endian => every
// odd 32-bit word is a high word == 0 (values in [0,100000)). Probability of
// 64 consecutive zero odd-words in genuine int32 data ~ (1e-5)^64 ~ 0.
__global__ void detect_idx_kernel(const int* __restrict__ ei, int* __restrict__ flag) {
    int l = threadIdx.x;                 // 0..63
    int v = ei[2 * l + 1];
    // OR-reduce across wave
    for (int off = 1; off < 64; off <<= 1) v |= __shfl_xor(v, off);
    if (l == 0) *flag = (v == 0) ? 1 : 0;   // 1 => int64 layout
}

// ---------------------------------------------------------------------------
// Kernel 1: h = x @ W  (fp32 vector GEMM) + fused a_src/a_dst dots.
// block=256: 8 rows/block, thread t -> row (t>>5), colgroup cg=(t&31) (4 cols).
__global__ __launch_bounds__(256) void gemm_att_kernel(
        const float* __restrict__ x, const float* __restrict__ W,
        const float* __restrict__ att_src, const float* __restrict__ att_dst,
        float* __restrict__ h, float* __restrict__ a_src, float* __restrict__ a_dst) {
    int t = threadIdx.x;
    int row = blockIdx.x * 8 + (t >> 5);
    int cg = t & 31;
    if (row >= NN) return;

    const float4* __restrict__ Wv = (const float4*)W;  // [128][32] float4
    const float* __restrict__ xr = x + (size_t)row * F_IN;
    float4 acc = make_float4(0.f, 0.f, 0.f, 0.f);
#pragma unroll 8
    for (int k = 0; k < F_IN; ++k) {
        float xk = xr[k];                  // broadcast across 32 lanes (L1)
        float4 w4 = Wv[k * 32 + cg];       // coalesced 512B per 32 lanes
        acc.x += xk * w4.x; acc.y += xk * w4.y;
        acc.z += xk * w4.z; acc.w += xk * w4.w;
    }
    ((float4*)h)[(size_t)row * 32 + cg] = acc;

    // fused attention dots: cols 4cg..4cg+3 all in head hd = cg>>3
    float4 as4 = ((const float4*)att_src)[cg];
    float4 ad4 = ((const float4*)att_dst)[cg];
    float ps = acc.x * as4.x + acc.y * as4.y + acc.z * as4.z + acc.w * as4.w;
    float pd = acc.x * ad4.x + acc.y * ad4.y + acc.z * ad4.z + acc.w * ad4.w;
    // reduce over the 8 lanes sharing (row, head): lanes are 8-aligned groups
    for (int off = 1; off < 8; off <<= 1) {
        ps += __shfl_xor(ps, off);
        pd += __shfl_xor(pd, off);
    }
    if ((cg & 7) == 0) {
        int hd = cg >> 3;
        a_src[row * HEADS + hd] = ps;
        a_dst[row * HEADS + hd] = pd;
    }
}

// ---------------------------------------------------------------------------
// Kernel 2: s[i] = exp(leaky(a_src[i]+a_dst[i]))  (self-loop contribution)
__global__ __launch_bounds__(256) void init_s_kernel(
        const float* __restrict__ a_src, const float* __restrict__ a_dst,
        float* __restrict__ s) {
    int i = blockIdx.x * 256 + threadIdx.x;
    if (i >= NN * HEADS) return;
    float e = a_src[i] + a_dst[i];
    e = (e < 0.f) ? NEG_SLOPE * e : e;
    s[i] = __expf(e);
}

// ---------------------------------------------------------------------------
// Kernel 3: per-edge exp accumulation into s[dst]
__global__ __launch_bounds__(256) void edge_sum_kernel(
        const int* __restrict__ ei, const int* __restrict__ flag,
        const float* __restrict__ a_src, const float* __restrict__ a_dst,
        float* __restrict__ s) {
    int e = blockIdx.x * 256 + threadIdx.x;
    if (e >= NE) return;
    int is64 = *flag;
    int src = is64 ? ei[2 * e] : ei[e];
    int dst = is64 ? ei[2 * NE + 2 * e] : ei[NE + e];
    float4 as = ((const float4*)a_src)[src];
    float4 ad = ((const float4*)a_dst)[dst];
    float ex, w;
    ex = as.x + ad.x; ex = (ex < 0.f) ? NEG_SLOPE * ex : ex; w = __expf(ex);
    atomicAdd(&s[dst * 4 + 0], w);
    ex = as.y + ad.y; ex = (ex < 0.f) ? NEG_SLOPE * ex : ex; w = __expf(ex);
    atomicAdd(&s[dst * 4 + 1], w);
    ex = as.z + ad.z; ex = (ex < 0.f) ? NEG_SLOPE * ex : ex; w = __expf(ex);
    atomicAdd(&s[dst * 4 + 2], w);
    ex = as.w + ad.w; ex = (ex < 0.f) ? NEG_SLOPE * ex : ex; w = __expf(ex);
    atomicAdd(&s[dst * 4 + 3], w);
}

// ---------------------------------------------------------------------------
// Kernel 4: edge aggregation. One 64-lane wave per edge; lane l handles
// cols 2l,2l+1 (head = l>>4). out[dst] += alpha * h[src].
__global__ __launch_bounds__(256) void edge_aggr_kernel(
        const int* __restrict__ ei, const int* __restrict__ flag,
        const float* __restrict__ a_src, const float* __restrict__ a_dst,
        const float* __restrict__ s, const float* __restrict__ h,
        float* __restrict__ out) {
    long long gt = (long long)blockIdx.x * 256 + threadIdx.x;
    int e = (int)(gt >> 6);
    int lane = threadIdx.x & 63;
    if (e >= NE) return;
    int is64 = *flag;
    int src = is64 ? ei[2 * e] : ei[e];
    int dst = is64 ? ei[2 * NE + 2 * e] : ei[NE + e];
    int hd = lane >> 4;
    float ex = a_src[src * 4 + hd] + a_dst[dst * 4 + hd];
    ex = (ex < 0.f) ? NEG_SLOPE * ex : ex;
    float alpha = __expf(ex) / (s[dst * 4 + hd] + 1e-16f);
    float2 hv = ((const float2*)h)[(size_t)src * 64 + lane];
    atomicAdd(&out[(size_t)dst * HC + 2 * lane + 0], alpha * hv.x);
    atomicAdd(&out[(size_t)dst * HC + 2 * lane + 1], alpha * hv.y);
}

// ---------------------------------------------------------------------------
// Kernel 5: finalize — add self-loop message + bias, tanh, in place on out.
__global__ __launch_bounds__(256) void finalize_kernel(
        const float* __restrict__ h, const float* __restrict__ a_src,
        const float* __restrict__ a_dst, const float* __restrict__ s,
        const float* __restrict__ bias, float* __restrict__ out) {
    int i = blockIdx.x * 256 + threadIdx.x;   // over NN*32 float4 groups
    if (i >= NN * 32) return;
    int n = i >> 5;
    int cg = i & 31;
    int hd = cg >> 3;
    float ex = a_src[n * 4 + hd] + a_dst[n * 4 + hd];
    ex = (ex < 0.f) ? NEG_SLOPE * ex : ex;
    float alpha = __expf(ex) / (s[n * 4 + hd] + 1e-16f);
    float4 hv = ((const float4*)h)[i];
    float4 o = ((float4*)out)[i];
    float4 b = ((const float4*)bias)[cg];
    o.x = tanhf(o.x + alpha * hv.x + b.x);
    o.y = tanhf(o.y + alpha * hv.y + b.y);
    o.z = tanhf(o.z + alpha * hv.z + b.z);
    o.w = tanhf(o.w + alpha * hv.w + b.w);
    ((float4*)out)[i] = o;
}

// ---------------------------------------------------------------------------
extern "C" void kernel_launch(void* const* d_in, const int* in_sizes, int n_in,
                              void* d_out, int out_size, void* d_ws, size_t ws_size,
                              hipStream_t stream) {
    const float* x       = (const float*)d_in[0];
    const int*   ei      = (const int*)  d_in[1];
    const float* W       = (const float*)d_in[2];
    const float* att_src = (const float*)d_in[3];
    const float* att_dst = (const float*)d_in[4];
    const float* bias    = (const float*)d_in[5];
    float* out = (float*)d_out;

    float* ws    = (float*)d_ws;
    float* h     = ws;                         // NN*128 floats (51.2 MB)
    float* a_src = h + (size_t)NN * HC;        // NN*4
    float* a_dst = a_src + (size_t)NN * HEADS; // NN*4
    float* s     = a_dst + (size_t)NN * HEADS; // NN*4
    int*   flag  = (int*)(s + (size_t)NN * HEADS);

    hipMemsetAsync(d_out, 0, (size_t)NN * HC * sizeof(float), stream);

    hipLaunchKernelGGL(detect_idx_kernel, dim3(1), dim3(64), 0, stream, ei, flag);

    hipLaunchKernelGGL(gemm_att_kernel, dim3((NN + 7) / 8), dim3(256), 0, stream,
                       x, W, att_src, att_dst, h, a_src, a_dst);

    hipLaunchKernelGGL(init_s_kernel, dim3((NN * HEADS + 255) / 256), dim3(256), 0, stream,
                       a_src, a_dst, s);

    hipLaunchKernelGGL(edge_sum_kernel, dim3((NE + 255) / 256), dim3(256), 0, stream,
                       ei, flag, a_src, a_dst, s);

    // one wave (64 lanes) per edge -> 4 edges per 256-thread block
    hipLaunchKernelGGL(edge_aggr_kernel, dim3((NE + 3) / 4), dim3(256), 0, stream,
                       ei, flag, a_src, a_dst, s, h, out);

    hipLaunchKernelGGL(finalize_kernel, dim3((NN * 32 + 255) / 256), dim3(256), 0, stream,
                       h, a_src, a_dst, s, bias, out);
}

// Round 2
// 660.306 us; speedup vs baseline: 3.0253x; 3.0253x over previous
//
#include <hip/hip_runtime.h>
#include <math.h>

#define NN 100000
#define NE 1600000
#define F_IN 128
#define HEADS 4
#define HC 128
#define NEG_SLOPE 0.2f
#define NB 391   // (NN+255)/256 scan blocks

// ---------------------------------------------------------------------------
// Kernel 0: detect int64 vs int32 edge_index (odd words all-zero => int64).
__global__ void detect_idx_kernel(const int* __restrict__ ei, int* __restrict__ flag) {
    int l = threadIdx.x;
    int v = ei[2 * l + 1];
    for (int off = 1; off < 64; off <<= 1) v |= __shfl_xor(v, off);
    if (l == 0) *flag = (v == 0) ? 1 : 0;
}

// ---------------------------------------------------------------------------
// Kernel 1: h = x @ W (fp32 vector GEMM) + fused a_src/a_dst dots.
__global__ __launch_bounds__(256) void gemm_att_kernel(
        const float* __restrict__ x, const float* __restrict__ W,
        const float* __restrict__ att_src, const float* __restrict__ att_dst,
        float* __restrict__ h, float* __restrict__ a_src, float* __restrict__ a_dst) {
    int t = threadIdx.x;
    int row = blockIdx.x * 8 + (t >> 5);
    int cg = t & 31;
    if (row >= NN) return;

    const float4* __restrict__ Wv = (const float4*)W;
    const float* __restrict__ xr = x + (size_t)row * F_IN;
    float4 acc = make_float4(0.f, 0.f, 0.f, 0.f);
#pragma unroll 8
    for (int k = 0; k < F_IN; ++k) {
        float xk = xr[k];
        float4 w4 = Wv[k * 32 + cg];
        acc.x += xk * w4.x; acc.y += xk * w4.y;
        acc.z += xk * w4.z; acc.w += xk * w4.w;
    }
    ((float4*)h)[(size_t)row * 32 + cg] = acc;

    float4 as4 = ((const float4*)att_src)[cg];
    float4 ad4 = ((const float4*)att_dst)[cg];
    float ps = acc.x * as4.x + acc.y * as4.y + acc.z * as4.z + acc.w * as4.w;
    float pd = acc.x * ad4.x + acc.y * ad4.y + acc.z * ad4.z + acc.w * ad4.w;
    for (int off = 1; off < 8; off <<= 1) {
        ps += __shfl_xor(ps, off);
        pd += __shfl_xor(pd, off);
    }
    if ((cg & 7) == 0) {
        int hd = cg >> 3;
        a_src[row * HEADS + hd] = ps;
        a_dst[row * HEADS + hd] = pd;
    }
}

// ---------------------------------------------------------------------------
// Kernel 2: degree histogram over dst.
__global__ __launch_bounds__(256) void hist_kernel(
        const int* __restrict__ ei, const int* __restrict__ flag,
        int* __restrict__ deg) {
    int e = blockIdx.x * 256 + threadIdx.x;
    if (e >= NE) return;
    int is64 = *flag;
    int dst = is64 ? ei[2 * NE + 2 * e] : ei[NE + e];
    atomicAdd(&deg[dst], 1);
}

// ---------------------------------------------------------------------------
// Kernel 3a: per-block exclusive scan + block sums.
__global__ __launch_bounds__(256) void scanA_kernel(
        const int* __restrict__ deg, int* __restrict__ pre, int* __restrict__ bsum) {
    __shared__ int sd[256];
    int t = threadIdx.x;
    int i = blockIdx.x * 256 + t;
    int v = (i < NN) ? deg[i] : 0;
    sd[t] = v;
    __syncthreads();
    for (int off = 1; off < 256; off <<= 1) {
        int u = (t >= off) ? sd[t - off] : 0;
        __syncthreads();
        sd[t] += u;
        __syncthreads();
    }
    if (i < NN) pre[i] = sd[t] - v;           // exclusive within block
    if (t == 255) bsum[blockIdx.x] = sd[255]; // block total
}

// Kernel 3b: scan 391 block sums (single block of 512).
__global__ __launch_bounds__(512) void scanB_kernel(
        const int* __restrict__ bsum, int* __restrict__ boff) {
    __shared__ int sd[512];
    int t = threadIdx.x;
    int v = (t < NB) ? bsum[t] : 0;
    sd[t] = v;
    __syncthreads();
    for (int off = 1; off < 512; off <<= 1) {
        int u = (t >= off) ? sd[t - off] : 0;
        __syncthreads();
        sd[t] += u;
        __syncthreads();
    }
    if (t < NB) boff[t] = sd[t] - v;          // exclusive
}

// Kernel 3c: combine -> offsets, init cursor.
__global__ __launch_bounds__(256) void scanC_kernel(
        const int* __restrict__ pre, const int* __restrict__ boff,
        int* __restrict__ offsets, int* __restrict__ cursor) {
    int i = blockIdx.x * 256 + threadIdx.x;
    if (i >= NN) return;
    int o = pre[i] + boff[blockIdx.x];
    offsets[i] = o;
    cursor[i] = o;
}

// ---------------------------------------------------------------------------
// Kernel 4: scatter src ids into dst-CSR.
__global__ __launch_bounds__(256) void scatter_kernel(
        const int* __restrict__ ei, const int* __restrict__ flag,
        int* __restrict__ cursor, int* __restrict__ csr_src) {
    int e = blockIdx.x * 256 + threadIdx.x;
    if (e >= NE) return;
    int is64 = *flag;
    int src = is64 ? ei[2 * e] : ei[e];
    int dst = is64 ? ei[2 * NE + 2 * e] : ei[NE + e];
    int pos = atomicAdd(&cursor[dst], 1);
    csr_src[pos] = src;
}

// ---------------------------------------------------------------------------
// Kernel 5: per-node aggregation. One wave per dst. Lane l -> cols 2l,2l+1,
// head = l>>4. Accumulates msg and softmax denominator in registers,
// applies self-loop + bias + tanh. No atomics.
__global__ __launch_bounds__(256) void gat_aggr_kernel(
        const int* __restrict__ offsets, const int* __restrict__ deg,
        const int* __restrict__ csr_src,
        const float* __restrict__ a_src, const float* __restrict__ a_dst,
        const float* __restrict__ h, const float* __restrict__ bias,
        float* __restrict__ out) {
    int wid = (blockIdx.x * 256 + threadIdx.x) >> 6;  // dst node
    int lane = threadIdx.x & 63;
    if (wid >= NN) return;
    int dst = wid;
    int hd = lane >> 4;

    float ad = a_dst[dst * 4 + hd];
    int start = offsets[dst];
    int n = deg[dst];
    const float2* __restrict__ h2 = (const float2*)h;

    float accx = 0.f, accy = 0.f, sw = 0.f;
    int j = 0;
    for (; j + 1 < n; j += 2) {   // 2-way unroll for latency hiding
        int s0 = csr_src[start + j];
        int s1 = csr_src[start + j + 1];
        float as0 = a_src[s0 * 4 + hd];
        float as1 = a_src[s1 * 4 + hd];
        float2 h0 = h2[(size_t)s0 * 64 + lane];
        float2 h1 = h2[(size_t)s1 * 64 + lane];
        float e0 = as0 + ad; e0 = (e0 < 0.f) ? NEG_SLOPE * e0 : e0;
        float e1 = as1 + ad; e1 = (e1 < 0.f) ? NEG_SLOPE * e1 : e1;
        float w0 = __expf(e0), w1 = __expf(e1);
        accx += w0 * h0.x + w1 * h1.x;
        accy += w0 * h0.y + w1 * h1.y;
        sw   += w0 + w1;
    }
    if (j < n) {
        int s0 = csr_src[start + j];
        float as0 = a_src[s0 * 4 + hd];
        float2 h0 = h2[(size_t)s0 * 64 + lane];
        float e0 = as0 + ad; e0 = (e0 < 0.f) ? NEG_SLOPE * e0 : e0;
        float w0 = __expf(e0);
        accx += w0 * h0.x; accy += w0 * h0.y; sw += w0;
    }
    // self-loop
    {
        float as = a_src[dst * 4 + hd];
        float e0 = as + ad; e0 = (e0 < 0.f) ? NEG_SLOPE * e0 : e0;
        float w0 = __expf(e0);
        float2 hv = h2[(size_t)dst * 64 + lane];
        accx += w0 * hv.x; accy += w0 * hv.y; sw += w0;
    }
    float inv = 1.f / (sw + 1e-16f);
    float2 b2 = ((const float2*)bias)[lane];
    float2 o;
    o.x = tanhf(accx * inv + b2.x);
    o.y = tanhf(accy * inv + b2.y);
    ((float2*)out)[(size_t)dst * 64 + lane] = o;
}

// ---------------------------------------------------------------------------
extern "C" void kernel_launch(void* const* d_in, const int* in_sizes, int n_in,
                              void* d_out, int out_size, void* d_ws, size_t ws_size,
                              hipStream_t stream) {
    const float* x       = (const float*)d_in[0];
    const int*   ei      = (const int*)  d_in[1];
    const float* W       = (const float*)d_in[2];
    const float* att_src = (const float*)d_in[3];
    const float* att_dst = (const float*)d_in[4];
    const float* bias    = (const float*)d_in[5];
    float* out = (float*)d_out;

    float* ws    = (float*)d_ws;
    float* h     = ws;                          // NN*128 floats
    float* a_src = h + (size_t)NN * HC;         // NN*4
    float* a_dst = a_src + (size_t)NN * HEADS;  // NN*4
    int* flag    = (int*)(a_dst + (size_t)NN * HEADS);
    int* deg     = flag + 4;
    int* pre     = deg + NN;
    int* bsum    = pre + NN;       // 512
    int* boff    = bsum + 512;     // 512
    int* offsets = boff + 512;
    int* cursor  = offsets + NN;
    int* csr_src = cursor + NN;    // NE

    hipMemsetAsync(deg, 0, NN * sizeof(int), stream);

    hipLaunchKernelGGL(detect_idx_kernel, dim3(1), dim3(64), 0, stream, ei, flag);

    hipLaunchKernelGGL(gemm_att_kernel, dim3((NN + 7) / 8), dim3(256), 0, stream,
                       x, W, att_src, att_dst, h, a_src, a_dst);

    hipLaunchKernelGGL(hist_kernel, dim3((NE + 255) / 256), dim3(256), 0, stream,
                       ei, flag, deg);

    hipLaunchKernelGGL(scanA_kernel, dim3(NB), dim3(256), 0, stream, deg, pre, bsum);
    hipLaunchKernelGGL(scanB_kernel, dim3(1), dim3(512), 0, stream, bsum, boff);
    hipLaunchKernelGGL(scanC_kernel, dim3(NB), dim3(256), 0, stream,
                       pre, boff, offsets, cursor);

    hipLaunchKernelGGL(scatter_kernel, dim3((NE + 255) / 256), dim3(256), 0, stream,
                       ei, flag, cursor, csr_src);

    hipLaunchKernelGGL(gat_aggr_kernel, dim3((NN * 64 + 255) / 256), dim3(256), 0, stream,
                       offsets, deg, csr_src, a_src, a_dst, h, bias, out);
}

// Round 3
// 537.500 us; speedup vs baseline: 3.7166x; 1.2285x over previous
//
#include <hip/hip_runtime.h>
#include <math.h>

#define NN 100000
#define NE 1600000
#define F_IN 128
#define HEADS 4
#define HC 128
#define NEG_SLOPE 0.2f
#define NB 391   // (NN+255)/256 scan blocks

typedef __attribute__((ext_vector_type(8))) short bf16x8;
typedef __attribute__((ext_vector_type(4))) float f32x4;

static __device__ __forceinline__ short f2bf_rne(float f) {
    unsigned u = __float_as_uint(f);
    unsigned r = (u + 0x7FFFu + ((u >> 16) & 1u)) >> 16;
    return (short)r;
}
static __device__ __forceinline__ float bf2f(short s) {
    return __uint_as_float(((unsigned)(unsigned short)s) << 16);
}

// ---------------------------------------------------------------------------
// Kernel 0: detect int64 vs int32 edge_index (odd words all-zero => int64).
__global__ void detect_idx_kernel(const int* __restrict__ ei, int* __restrict__ flag) {
    int l = threadIdx.x;
    int v = ei[2 * l + 1];
    for (int off = 1; off < 64; off <<= 1) v |= __shfl_xor(v, off);
    if (l == 0) *flag = (v == 0) ? 1 : 0;
}

// ---------------------------------------------------------------------------
// Kernel 1a: W [128][128] fp32 -> Wt_hi/Wt_lo [n][k] bf16 (transposed, split).
__global__ __launch_bounds__(256) void prepw_kernel(
        const float* __restrict__ W, short* __restrict__ wt_hi, short* __restrict__ wt_lo) {
    int i = blockIdx.x * 256 + threadIdx.x;
    if (i >= F_IN * HC) return;
    int k = i >> 7, n = i & 127;
    float f = W[k * HC + n];
    short hb = f2bf_rne(f);
    wt_hi[n * F_IN + k] = hb;
    wt_lo[n * F_IN + k] = f2bf_rne(f - bf2f(hb));
}

// ---------------------------------------------------------------------------
// Kernel 1b: h = x @ W via split-bf16 MFMA (fp32-equivalent accuracy).
// One wave per 16-row strip. A[m=lane&15][k=quad*8+j]; B[k][n=lane&15];
// D col=lane&15, row=quad*4+reg (m89-verified layouts).
__global__ __launch_bounds__(256) void mfma_gemm_kernel(
        const float* __restrict__ x, const short* __restrict__ wt_hi,
        const short* __restrict__ wt_lo, float* __restrict__ h) {
    int strip = (blockIdx.x * 256 + threadIdx.x) >> 6;
    int lane = threadIdx.x & 63;
    if (strip >= NN / 16) return;
    int l15 = lane & 15;
    int q = lane >> 4;

    f32x4 acc[8];
#pragma unroll
    for (int nt = 0; nt < 8; ++nt) acc[nt] = (f32x4){0.f, 0.f, 0.f, 0.f};

    const float* xp = x + (size_t)(strip * 16 + l15) * F_IN + q * 8;

#pragma unroll
    for (int ki = 0; ki < 4; ++ki) {
        float4 v0 = *(const float4*)(xp + ki * 32);
        float4 v1 = *(const float4*)(xp + ki * 32 + 4);
        float vv[8] = {v0.x, v0.y, v0.z, v0.w, v1.x, v1.y, v1.z, v1.w};
        bf16x8 a_hi, a_lo;
#pragma unroll
        for (int j = 0; j < 8; ++j) {
            short hb = f2bf_rne(vv[j]);
            a_hi[j] = hb;
            a_lo[j] = f2bf_rne(vv[j] - bf2f(hb));
        }
        int koff = ki * 32 + q * 8;
#pragma unroll
        for (int nt = 0; nt < 8; ++nt) {
            int widx = (nt * 16 + l15) * F_IN + koff;
            bf16x8 b_hi = *(const bf16x8*)(wt_hi + widx);
            bf16x8 b_lo = *(const bf16x8*)(wt_lo + widx);
            acc[nt] = __builtin_amdgcn_mfma_f32_16x16x32_bf16(a_hi, b_hi, acc[nt], 0, 0, 0);
            acc[nt] = __builtin_amdgcn_mfma_f32_16x16x32_bf16(a_lo, b_hi, acc[nt], 0, 0, 0);
            acc[nt] = __builtin_amdgcn_mfma_f32_16x16x32_bf16(a_hi, b_lo, acc[nt], 0, 0, 0);
        }
    }

    int orow = strip * 16 + q * 4;
#pragma unroll
    for (int nt = 0; nt < 8; ++nt)
#pragma unroll
        for (int r = 0; r < 4; ++r)
            h[(size_t)(orow + r) * HC + nt * 16 + l15] = acc[nt][r];
}

// ---------------------------------------------------------------------------
// Kernel 1c: attention dots a_src/a_dst from h.
__global__ __launch_bounds__(256) void att_kernel(
        const float* __restrict__ h, const float* __restrict__ att_src,
        const float* __restrict__ att_dst, float* __restrict__ a_src,
        float* __restrict__ a_dst) {
    int idx = blockIdx.x * 256 + threadIdx.x;   // over NN*HEADS
    if (idx >= NN * HEADS) return;
    int node = idx >> 2;
    int hd = idx & 3;
    const float4* hp = (const float4*)(h + (size_t)node * HC + hd * 32);
    const float4* as = (const float4*)(att_src + hd * 32);
    const float4* ad = (const float4*)(att_dst + hd * 32);
    float ps = 0.f, pd = 0.f;
#pragma unroll
    for (int i = 0; i < 8; ++i) {
        float4 hv = hp[i];
        float4 a = as[i], d = ad[i];
        ps += hv.x * a.x + hv.y * a.y + hv.z * a.z + hv.w * a.w;
        pd += hv.x * d.x + hv.y * d.y + hv.z * d.z + hv.w * d.w;
    }
    a_src[idx] = ps;
    a_dst[idx] = pd;
}

// ---------------------------------------------------------------------------
// Kernel 2: degree histogram over dst.
__global__ __launch_bounds__(256) void hist_kernel(
        const int* __restrict__ ei, const int* __restrict__ flag,
        int* __restrict__ deg) {
    int e = blockIdx.x * 256 + threadIdx.x;
    if (e >= NE) return;
    int is64 = *flag;
    int dst = is64 ? ei[2 * NE + 2 * e] : ei[NE + e];
    atomicAdd(&deg[dst], 1);
}

// ---------------------------------------------------------------------------
// Kernel 3a: per-block exclusive scan + block sums.
__global__ __launch_bounds__(256) void scanA_kernel(
        const int* __restrict__ deg, int* __restrict__ pre, int* __restrict__ bsum) {
    __shared__ int sd[256];
    int t = threadIdx.x;
    int i = blockIdx.x * 256 + t;
    int v = (i < NN) ? deg[i] : 0;
    sd[t] = v;
    __syncthreads();
    for (int off = 1; off < 256; off <<= 1) {
        int u = (t >= off) ? sd[t - off] : 0;
        __syncthreads();
        sd[t] += u;
        __syncthreads();
    }
    if (i < NN) pre[i] = sd[t] - v;
    if (t == 255) bsum[blockIdx.x] = sd[255];
}

// Kernel 3b: scan block sums (single block of 512).
__global__ __launch_bounds__(512) void scanB_kernel(
        const int* __restrict__ bsum, int* __restrict__ boff) {
    __shared__ int sd[512];
    int t = threadIdx.x;
    int v = (t < NB) ? bsum[t] : 0;
    sd[t] = v;
    __syncthreads();
    for (int off = 1; off < 512; off <<= 1) {
        int u = (t >= off) ? sd[t - off] : 0;
        __syncthreads();
        sd[t] += u;
        __syncthreads();
    }
    if (t < NB) boff[t] = sd[t] - v;
}

// Kernel 3c: combine -> offsets, init cursor.
__global__ __launch_bounds__(256) void scanC_kernel(
        const int* __restrict__ pre, const int* __restrict__ boff,
        int* __restrict__ offsets, int* __restrict__ cursor) {
    int i = blockIdx.x * 256 + threadIdx.x;
    if (i >= NN) return;
    int o = pre[i] + boff[blockIdx.x];
    offsets[i] = o;
    cursor[i] = o;
}

// ---------------------------------------------------------------------------
// Kernel 4: scatter src ids into dst-CSR.
__global__ __launch_bounds__(256) void scatter_kernel(
        const int* __restrict__ ei, const int* __restrict__ flag,
        int* __restrict__ cursor, int* __restrict__ csr_src) {
    int e = blockIdx.x * 256 + threadIdx.x;
    if (e >= NE) return;
    int is64 = *flag;
    int src = is64 ? ei[2 * e] : ei[e];
    int dst = is64 ? ei[2 * NE + 2 * e] : ei[NE + e];
    int pos = atomicAdd(&cursor[dst], 1);
    csr_src[pos] = src;
}

// ---------------------------------------------------------------------------
// Kernel 5: per-node aggregation. One wave per dst; register accumulation.
__global__ __launch_bounds__(256) void gat_aggr_kernel(
        const int* __restrict__ offsets, const int* __restrict__ deg,
        const int* __restrict__ csr_src,
        const float* __restrict__ a_src, const float* __restrict__ a_dst,
        const float* __restrict__ h, const float* __restrict__ bias,
        float* __restrict__ out) {
    int wid = (blockIdx.x * 256 + threadIdx.x) >> 6;
    int lane = threadIdx.x & 63;
    if (wid >= NN) return;
    int dst = wid;
    int hd = lane >> 4;

    float ad = a_dst[dst * 4 + hd];
    int start = offsets[dst];
    int n = deg[dst];
    const float2* __restrict__ h2 = (const float2*)h;

    float accx = 0.f, accy = 0.f, sw = 0.f;
    int j = 0;
    for (; j + 1 < n; j += 2) {
        int s0 = csr_src[start + j];
        int s1 = csr_src[start + j + 1];
        float as0 = a_src[s0 * 4 + hd];
        float as1 = a_src[s1 * 4 + hd];
        float2 h0 = h2[(size_t)s0 * 64 + lane];
        float2 h1 = h2[(size_t)s1 * 64 + lane];
        float e0 = as0 + ad; e0 = (e0 < 0.f) ? NEG_SLOPE * e0 : e0;
        float e1 = as1 + ad; e1 = (e1 < 0.f) ? NEG_SLOPE * e1 : e1;
        float w0 = __expf(e0), w1 = __expf(e1);
        accx += w0 * h0.x + w1 * h1.x;
        accy += w0 * h0.y + w1 * h1.y;
        sw   += w0 + w1;
    }
    if (j < n) {
        int s0 = csr_src[start + j];
        float as0 = a_src[s0 * 4 + hd];
        float2 h0 = h2[(size_t)s0 * 64 + lane];
        float e0 = as0 + ad; e0 = (e0 < 0.f) ? NEG_SLOPE * e0 : e0;
        float w0 = __expf(e0);
        accx += w0 * h0.x; accy += w0 * h0.y; sw += w0;
    }
    {
        float as = a_src[dst * 4 + hd];
        float e0 = as + ad; e0 = (e0 < 0.f) ? NEG_SLOPE * e0 : e0;
        float w0 = __expf(e0);
        float2 hv = h2[(size_t)dst * 64 + lane];
        accx += w0 * hv.x; accy += w0 * hv.y; sw += w0;
    }
    float inv = 1.f / (sw + 1e-16f);
    float2 b2 = ((const float2*)bias)[lane];
    float2 o;
    o.x = tanhf(accx * inv + b2.x);
    o.y = tanhf(accy * inv + b2.y);
    ((float2*)out)[(size_t)dst * 64 + lane] = o;
}

// ---------------------------------------------------------------------------
extern "C" void kernel_launch(void* const* d_in, const int* in_sizes, int n_in,
                              void* d_out, int out_size, void* d_ws, size_t ws_size,
                              hipStream_t stream) {
    const float* x       = (const float*)d_in[0];
    const int*   ei      = (const int*)  d_in[1];
    const float* W       = (const float*)d_in[2];
    const float* att_src = (const float*)d_in[3];
    const float* att_dst = (const float*)d_in[4];
    const float* bias    = (const float*)d_in[5];
    float* out = (float*)d_out;

    float* ws    = (float*)d_ws;
    float* h     = ws;                          // NN*128 floats
    float* a_src = h + (size_t)NN * HC;         // NN*4
    float* a_dst = a_src + (size_t)NN * HEADS;  // NN*4
    short* wt_hi = (short*)(a_dst + (size_t)NN * HEADS);  // 16384 shorts
    short* wt_lo = wt_hi + F_IN * HC;                     // 16384 shorts
    int* flag    = (int*)(wt_lo + F_IN * HC);
    int* deg     = flag + 4;
    int* pre     = deg + NN;
    int* bsum    = pre + NN;       // 512
    int* boff    = bsum + 512;     // 512
    int* offsets = boff + 512;
    int* cursor  = offsets + NN;
    int* csr_src = cursor + NN;    // NE

    hipMemsetAsync(deg, 0, NN * sizeof(int), stream);

    hipLaunchKernelGGL(detect_idx_kernel, dim3(1), dim3(64), 0, stream, ei, flag);

    hipLaunchKernelGGL(prepw_kernel, dim3(64), dim3(256), 0, stream, W, wt_hi, wt_lo);

    hipLaunchKernelGGL(hist_kernel, dim3((NE + 255) / 256), dim3(256), 0, stream,
                       ei, flag, deg);

    hipLaunchKernelGGL(mfma_gemm_kernel, dim3((NN / 16 + 3) / 4), dim3(256), 0, stream,
                       x, wt_hi, wt_lo, h);

    hipLaunchKernelGGL(att_kernel, dim3((NN * HEADS + 255) / 256), dim3(256), 0, stream,
                       h, att_src, att_dst, a_src, a_dst);

    hipLaunchKernelGGL(scanA_kernel, dim3(NB), dim3(256), 0, stream, deg, pre, bsum);
    hipLaunchKernelGGL(scanB_kernel, dim3(1), dim3(512), 0, stream, bsum, boff);
    hipLaunchKernelGGL(scanC_kernel, dim3(NB), dim3(256), 0, stream,
                       pre, boff, offsets, cursor);

    hipLaunchKernelGGL(scatter_kernel, dim3((NE + 255) / 256), dim3(256), 0, stream,
                       ei, flag, cursor, csr_src);

    hipLaunchKernelGGL(gat_aggr_kernel, dim3((NN * 64 + 255) / 256), dim3(256), 0, stream,
                       offsets, deg, csr_src, a_src, a_dst, h, bias, out);
}

// Round 4
// 463.282 us; speedup vs baseline: 4.3119x; 1.1602x over previous
//
#include <hip/hip_runtime.h>
#include <math.h>

#define NN 100000
#define NE 1600000
#define F_IN 128
#define HEADS 4
#define HC 128
#define NEG_SLOPE 0.2f
#define NB 391   // (NN+255)/256 scan blocks

typedef __attribute__((ext_vector_type(8))) short bf16x8;
typedef __attribute__((ext_vector_type(4))) float f32x4;

static __device__ __forceinline__ short f2bf_rne(float f) {
    unsigned u = __float_as_uint(f);
    unsigned r = (u + 0x7FFFu + ((u >> 16) & 1u)) >> 16;
    return (short)r;
}
static __device__ __forceinline__ float bf2f(short s) {
    return __uint_as_float(((unsigned)(unsigned short)s) << 16);
}

// ---------------------------------------------------------------------------
// Kernel 1: W prep (transpose + bf16 hi/lo split) + int64/int32 detect in blk 0.
__global__ __launch_bounds__(256) void prep_kernel(
        const float* __restrict__ W, short* __restrict__ wt_hi, short* __restrict__ wt_lo,
        const int* __restrict__ ei, int* __restrict__ flag) {
    if (blockIdx.x == 0 && threadIdx.x < 64) {
        int l = threadIdx.x;
        int v = ei[2 * l + 1];
        for (int off = 1; off < 64; off <<= 1) v |= __shfl_xor(v, off);
        if (l == 0) *flag = (v == 0) ? 1 : 0;   // 1 => int64 layout
    }
    int i = blockIdx.x * 256 + threadIdx.x;
    if (i >= F_IN * HC) return;
    int k = i >> 7, n = i & 127;
    float f = W[k * HC + n];
    short hb = f2bf_rne(f);
    wt_hi[n * F_IN + k] = hb;
    wt_lo[n * F_IN + k] = f2bf_rne(f - bf2f(hb));
}

// ---------------------------------------------------------------------------
// Kernel 2: h = x @ W via split-bf16 MFMA (fp32-equivalent), h stored as bf16.
// Fused epilogue: a_src/a_dst via 16-lane shuffle reductions.
// A[m=lane&15][k=quad*8+j]; B[k][n=lane&15]; D col=lane&15, row=quad*4+reg.
__global__ __launch_bounds__(256) void mfma_gemm_kernel(
        const float* __restrict__ x, const short* __restrict__ wt_hi,
        const short* __restrict__ wt_lo, const float* __restrict__ att_src,
        const float* __restrict__ att_dst, unsigned short* __restrict__ h_bf,
        float* __restrict__ a_src, float* __restrict__ a_dst) {
    int strip = (blockIdx.x * 256 + threadIdx.x) >> 6;
    int lane = threadIdx.x & 63;
    if (strip >= NN / 16) return;
    int l15 = lane & 15;
    int q = lane >> 4;

    f32x4 acc[8];
#pragma unroll
    for (int nt = 0; nt < 8; ++nt) acc[nt] = (f32x4){0.f, 0.f, 0.f, 0.f};

    const float* xp = x + (size_t)(strip * 16 + l15) * F_IN + q * 8;

#pragma unroll
    for (int ki = 0; ki < 4; ++ki) {
        float4 v0 = *(const float4*)(xp + ki * 32);
        float4 v1 = *(const float4*)(xp + ki * 32 + 4);
        float vv[8] = {v0.x, v0.y, v0.z, v0.w, v1.x, v1.y, v1.z, v1.w};
        bf16x8 a_hi, a_lo;
#pragma unroll
        for (int j = 0; j < 8; ++j) {
            short hb = f2bf_rne(vv[j]);
            a_hi[j] = hb;
            a_lo[j] = f2bf_rne(vv[j] - bf2f(hb));
        }
        int koff = ki * 32 + q * 8;
#pragma unroll
        for (int nt = 0; nt < 8; ++nt) {
            int widx = (nt * 16 + l15) * F_IN + koff;
            bf16x8 b_hi = *(const bf16x8*)(wt_hi + widx);
            bf16x8 b_lo = *(const bf16x8*)(wt_lo + widx);
            acc[nt] = __builtin_amdgcn_mfma_f32_16x16x32_bf16(a_hi, b_hi, acc[nt], 0, 0, 0);
            acc[nt] = __builtin_amdgcn_mfma_f32_16x16x32_bf16(a_lo, b_hi, acc[nt], 0, 0, 0);
            acc[nt] = __builtin_amdgcn_mfma_f32_16x16x32_bf16(a_hi, b_lo, acc[nt], 0, 0, 0);
        }
    }

    int orow = strip * 16 + q * 4;
    // store h as bf16
#pragma unroll
    for (int nt = 0; nt < 8; ++nt)
#pragma unroll
        for (int r = 0; r < 4; ++r)
            h_bf[(size_t)(orow + r) * HC + nt * 16 + l15] =
                (unsigned short)f2bf_rne(acc[nt][r]);

    // fused attention dots: head hd covers nt=2hd (col l15) and nt=2hd+1 (col 16+l15)
    float as0[4], as1[4], ad0[4], ad1[4];
#pragma unroll
    for (int hd = 0; hd < 4; ++hd) {
        as0[hd] = att_src[hd * 32 + l15];
        as1[hd] = att_src[hd * 32 + 16 + l15];
        ad0[hd] = att_dst[hd * 32 + l15];
        ad1[hd] = att_dst[hd * 32 + 16 + l15];
    }
#pragma unroll
    for (int r = 0; r < 4; ++r) {
#pragma unroll
        for (int hd = 0; hd < 4; ++hd) {
            float ps = acc[2 * hd][r] * as0[hd] + acc[2 * hd + 1][r] * as1[hd];
            float pd = acc[2 * hd][r] * ad0[hd] + acc[2 * hd + 1][r] * ad1[hd];
#pragma unroll
            for (int off = 1; off < 16; off <<= 1) {
                ps += __shfl_xor(ps, off);
                pd += __shfl_xor(pd, off);
            }
            if (l15 == 0) {
                int row = orow + r;
                a_src[row * 4 + hd] = ps;
                a_dst[row * 4 + hd] = pd;
            }
        }
    }
}

// ---------------------------------------------------------------------------
// Kernel 3: degree histogram over dst.
__global__ __launch_bounds__(256) void hist_kernel(
        const int* __restrict__ ei, const int* __restrict__ flag,
        int* __restrict__ deg) {
    int e = blockIdx.x * 256 + threadIdx.x;
    if (e >= NE) return;
    int is64 = *flag;
    int dst = is64 ? ei[2 * NE + 2 * e] : ei[NE + e];
    atomicAdd(&deg[dst], 1);
}

// ---------------------------------------------------------------------------
// Kernel 4a: per-block exclusive scan + block sums.
__global__ __launch_bounds__(256) void scanA_kernel(
        const int* __restrict__ deg, int* __restrict__ pre, int* __restrict__ bsum) {
    __shared__ int sd[256];
    int t = threadIdx.x;
    int i = blockIdx.x * 256 + t;
    int v = (i < NN) ? deg[i] : 0;
    sd[t] = v;
    __syncthreads();
    for (int off = 1; off < 256; off <<= 1) {
        int u = (t >= off) ? sd[t - off] : 0;
        __syncthreads();
        sd[t] += u;
        __syncthreads();
    }
    if (i < NN) pre[i] = sd[t] - v;
    if (t == 255) bsum[blockIdx.x] = sd[255];
}

// Kernel 4b: scan block sums.
__global__ __launch_bounds__(512) void scanB_kernel(
        const int* __restrict__ bsum, int* __restrict__ boff) {
    __shared__ int sd[512];
    int t = threadIdx.x;
    int v = (t < NB) ? bsum[t] : 0;
    sd[t] = v;
    __syncthreads();
    for (int off = 1; off < 512; off <<= 1) {
        int u = (t >= off) ? sd[t - off] : 0;
        __syncthreads();
        sd[t] += u;
        __syncthreads();
    }
    if (t < NB) boff[t] = sd[t] - v;
}

// Kernel 4c: combine -> offsets, init cursor.
__global__ __launch_bounds__(256) void scanC_kernel(
        const int* __restrict__ pre, const int* __restrict__ boff,
        int* __restrict__ offsets, int* __restrict__ cursor) {
    int i = blockIdx.x * 256 + threadIdx.x;
    if (i >= NN) return;
    int o = pre[i] + boff[blockIdx.x];
    offsets[i] = o;
    cursor[i] = o;
}

// ---------------------------------------------------------------------------
// Kernel 5: scatter src ids into dst-CSR.
__global__ __launch_bounds__(256) void scatter_kernel(
        const int* __restrict__ ei, const int* __restrict__ flag,
        int* __restrict__ cursor, int* __restrict__ csr_src) {
    int e = blockIdx.x * 256 + threadIdx.x;
    if (e >= NE) return;
    int is64 = *flag;
    int src = is64 ? ei[2 * e] : ei[e];
    int dst = is64 ? ei[2 * NE + 2 * e] : ei[NE + e];
    int pos = atomicAdd(&cursor[dst], 1);
    csr_src[pos] = src;
}

// ---------------------------------------------------------------------------
// Kernel 6: per-node aggregation. One wave per dst; bf16 h gather (256B/edge);
// register accumulation; self-loop + bias + tanh fused. No atomics.
__global__ __launch_bounds__(256) void gat_aggr_kernel(
        const int* __restrict__ offsets, const int* __restrict__ deg,
        const int* __restrict__ csr_src,
        const float* __restrict__ a_src, const float* __restrict__ a_dst,
        const unsigned* __restrict__ h2, const float* __restrict__ bias,
        float* __restrict__ out) {
    int wid = (blockIdx.x * 256 + threadIdx.x) >> 6;
    int lane = threadIdx.x & 63;
    if (wid >= NN) return;
    int dst = wid;
    int hd = lane >> 4;

    float ad = a_dst[dst * 4 + hd];
    int start = offsets[dst];
    int n = deg[dst];

    float accx = 0.f, accy = 0.f, sw = 0.f;
    int j = 0;
    for (; j + 1 < n; j += 2) {
        int s0 = csr_src[start + j];
        int s1 = csr_src[start + j + 1];
        float as0 = a_src[s0 * 4 + hd];
        float as1 = a_src[s1 * 4 + hd];
        unsigned u0 = h2[(size_t)s0 * 64 + lane];
        unsigned u1 = h2[(size_t)s1 * 64 + lane];
        float e0 = as0 + ad; e0 = (e0 < 0.f) ? NEG_SLOPE * e0 : e0;
        float e1 = as1 + ad; e1 = (e1 < 0.f) ? NEG_SLOPE * e1 : e1;
        float w0 = __expf(e0), w1 = __expf(e1);
        accx += w0 * __uint_as_float(u0 << 16) + w1 * __uint_as_float(u1 << 16);
        accy += w0 * __uint_as_float(u0 & 0xFFFF0000u) + w1 * __uint_as_float(u1 & 0xFFFF0000u);
        sw   += w0 + w1;
    }
    if (j < n) {
        int s0 = csr_src[start + j];
        float as0 = a_src[s0 * 4 + hd];
        unsigned u0 = h2[(size_t)s0 * 64 + lane];
        float e0 = as0 + ad; e0 = (e0 < 0.f) ? NEG_SLOPE * e0 : e0;
        float w0 = __expf(e0);
        accx += w0 * __uint_as_float(u0 << 16);
        accy += w0 * __uint_as_float(u0 & 0xFFFF0000u);
        sw += w0;
    }
    {   // self-loop
        float as = a_src[dst * 4 + hd];
        float e0 = as + ad; e0 = (e0 < 0.f) ? NEG_SLOPE * e0 : e0;
        float w0 = __expf(e0);
        unsigned uv = h2[(size_t)dst * 64 + lane];
        accx += w0 * __uint_as_float(uv << 16);
        accy += w0 * __uint_as_float(uv & 0xFFFF0000u);
        sw += w0;
    }
    float inv = 1.f / (sw + 1e-16f);
    float2 b2 = ((const float2*)bias)[lane];
    float2 o;
    o.x = tanhf(accx * inv + b2.x);
    o.y = tanhf(accy * inv + b2.y);
    ((float2*)out)[(size_t)dst * 64 + lane] = o;
}

// ---------------------------------------------------------------------------
extern "C" void kernel_launch(void* const* d_in, const int* in_sizes, int n_in,
                              void* d_out, int out_size, void* d_ws, size_t ws_size,
                              hipStream_t stream) {
    const float* x       = (const float*)d_in[0];
    const int*   ei      = (const int*)  d_in[1];
    const float* W       = (const float*)d_in[2];
    const float* att_src = (const float*)d_in[3];
    const float* att_dst = (const float*)d_in[4];
    const float* bias    = (const float*)d_in[5];
    float* out = (float*)d_out;

    unsigned short* h_bf = (unsigned short*)d_ws;            // NN*128 bf16
    float* a_src = (float*)(h_bf + (size_t)NN * HC);         // NN*4
    float* a_dst = a_src + (size_t)NN * HEADS;               // NN*4
    short* wt_hi = (short*)(a_dst + (size_t)NN * HEADS);     // 16384
    short* wt_lo = wt_hi + F_IN * HC;                        // 16384
    int* flag    = (int*)(wt_lo + F_IN * HC);
    int* deg     = flag + 4;
    int* pre     = deg + NN;
    int* bsum    = pre + NN;       // 512
    int* boff    = bsum + 512;     // 512
    int* offsets = boff + 512;
    int* cursor  = offsets + NN;
    int* csr_src = cursor + NN;    // NE

    hipMemsetAsync(deg, 0, NN * sizeof(int), stream);

    hipLaunchKernelGGL(prep_kernel, dim3(64), dim3(256), 0, stream,
                       W, wt_hi, wt_lo, ei, flag);

    hipLaunchKernelGGL(hist_kernel, dim3((NE + 255) / 256), dim3(256), 0, stream,
                       ei, flag, deg);

    hipLaunchKernelGGL(mfma_gemm_kernel, dim3((NN / 16 + 3) / 4), dim3(256), 0, stream,
                       x, wt_hi, wt_lo, att_src, att_dst, h_bf, a_src, a_dst);

    hipLaunchKernelGGL(scanA_kernel, dim3(NB), dim3(256), 0, stream, deg, pre, bsum);
    hipLaunchKernelGGL(scanB_kernel, dim3(1), dim3(512), 0, stream, bsum, boff);
    hipLaunchKernelGGL(scanC_kernel, dim3(NB), dim3(256), 0, stream,
                       pre, boff, offsets, cursor);

    hipLaunchKernelGGL(scatter_kernel, dim3((NE + 255) / 256), dim3(256), 0, stream,
                       ei, flag, cursor, csr_src);

    hipLaunchKernelGGL(gat_aggr_kernel, dim3((NN * 64 + 255) / 256), dim3(256), 0, stream,
                       offsets, deg, csr_src, a_src, a_dst, (const unsigned*)h_bf, bias, out);
}

// Round 5
// 387.271 us; speedup vs baseline: 5.1583x; 1.1963x over previous
//
#include <hip/hip_runtime.h>
#include <math.h>

#define NN 100000
#define NE 1600000
#define F_IN 128
#define HEADS 4
#define HC 128
#define NEG_SLOPE 0.2f
#define NB 391      // (NN+255)/256 scan blocks
#define NBKT 391    // buckets of 256 dst nodes: (NN+255)/256
#define BCAP 5120   // bucket capacity (mean 4096, sigma 64 -> +16 sigma)

typedef __attribute__((ext_vector_type(8))) short bf16x8;
typedef __attribute__((ext_vector_type(4))) float f32x4;

static __device__ __forceinline__ short f2bf_rne(float f) {
    unsigned u = __float_as_uint(f);
    unsigned r = (u + 0x7FFFu + ((u >> 16) & 1u)) >> 16;
    return (short)r;
}
static __device__ __forceinline__ float bf2f(short s) {
    return __uint_as_float(((unsigned)(unsigned short)s) << 16);
}

// ---------------------------------------------------------------------------
// Kernel 1: W prep (transpose + bf16 hi/lo split) + int64/int32 detect in blk 0.
__global__ __launch_bounds__(256) void prep_kernel(
        const float* __restrict__ W, short* __restrict__ wt_hi, short* __restrict__ wt_lo,
        const int* __restrict__ ei, int* __restrict__ flag) {
    if (blockIdx.x == 0 && threadIdx.x < 64) {
        int l = threadIdx.x;
        int v = ei[2 * l + 1];
        for (int off = 1; off < 64; off <<= 1) v |= __shfl_xor(v, off);
        if (l == 0) *flag = (v == 0) ? 1 : 0;   // 1 => int64 layout
    }
    int i = blockIdx.x * 256 + threadIdx.x;
    if (i >= F_IN * HC) return;
    int k = i >> 7, n = i & 127;
    float f = W[k * HC + n];
    short hb = f2bf_rne(f);
    wt_hi[n * F_IN + k] = hb;
    wt_lo[n * F_IN + k] = f2bf_rne(f - bf2f(hb));
}

// ---------------------------------------------------------------------------
// Kernel 2: h = x @ W via split-bf16 MFMA (fp32-equivalent), h stored as bf16.
// Fused epilogue: a_src/a_dst via 16-lane shuffle reductions.
__global__ __launch_bounds__(256) void mfma_gemm_kernel(
        const float* __restrict__ x, const short* __restrict__ wt_hi,
        const short* __restrict__ wt_lo, const float* __restrict__ att_src,
        const float* __restrict__ att_dst, unsigned short* __restrict__ h_bf,
        float* __restrict__ a_src, float* __restrict__ a_dst) {
    int strip = (blockIdx.x * 256 + threadIdx.x) >> 6;
    int lane = threadIdx.x & 63;
    if (strip >= NN / 16) return;
    int l15 = lane & 15;
    int q = lane >> 4;

    f32x4 acc[8];
#pragma unroll
    for (int nt = 0; nt < 8; ++nt) acc[nt] = (f32x4){0.f, 0.f, 0.f, 0.f};

    const float* xp = x + (size_t)(strip * 16 + l15) * F_IN + q * 8;

#pragma unroll
    for (int ki = 0; ki < 4; ++ki) {
        float4 v0 = *(const float4*)(xp + ki * 32);
        float4 v1 = *(const float4*)(xp + ki * 32 + 4);
        float vv[8] = {v0.x, v0.y, v0.z, v0.w, v1.x, v1.y, v1.z, v1.w};
        bf16x8 a_hi, a_lo;
#pragma unroll
        for (int j = 0; j < 8; ++j) {
            short hb = f2bf_rne(vv[j]);
            a_hi[j] = hb;
            a_lo[j] = f2bf_rne(vv[j] - bf2f(hb));
        }
        int koff = ki * 32 + q * 8;
#pragma unroll
        for (int nt = 0; nt < 8; ++nt) {
            int widx = (nt * 16 + l15) * F_IN + koff;
            bf16x8 b_hi = *(const bf16x8*)(wt_hi + widx);
            bf16x8 b_lo = *(const bf16x8*)(wt_lo + widx);
            acc[nt] = __builtin_amdgcn_mfma_f32_16x16x32_bf16(a_hi, b_hi, acc[nt], 0, 0, 0);
            acc[nt] = __builtin_amdgcn_mfma_f32_16x16x32_bf16(a_lo, b_hi, acc[nt], 0, 0, 0);
            acc[nt] = __builtin_amdgcn_mfma_f32_16x16x32_bf16(a_hi, b_lo, acc[nt], 0, 0, 0);
        }
    }

    int orow = strip * 16 + q * 4;
#pragma unroll
    for (int nt = 0; nt < 8; ++nt)
#pragma unroll
        for (int r = 0; r < 4; ++r)
            h_bf[(size_t)(orow + r) * HC + nt * 16 + l15] =
                (unsigned short)f2bf_rne(acc[nt][r]);

    float as0[4], as1[4], ad0[4], ad1[4];
#pragma unroll
    for (int hd = 0; hd < 4; ++hd) {
        as0[hd] = att_src[hd * 32 + l15];
        as1[hd] = att_src[hd * 32 + 16 + l15];
        ad0[hd] = att_dst[hd * 32 + l15];
        ad1[hd] = att_dst[hd * 32 + 16 + l15];
    }
#pragma unroll
    for (int r = 0; r < 4; ++r) {
#pragma unroll
        for (int hd = 0; hd < 4; ++hd) {
            float ps = acc[2 * hd][r] * as0[hd] + acc[2 * hd + 1][r] * as1[hd];
            float pd = acc[2 * hd][r] * ad0[hd] + acc[2 * hd + 1][r] * ad1[hd];
#pragma unroll
            for (int off = 1; off < 16; off <<= 1) {
                ps += __shfl_xor(ps, off);
                pd += __shfl_xor(pd, off);
            }
            if (l15 == 0) {
                int row = orow + r;
                a_src[row * 4 + hd] = ps;
                a_dst[row * 4 + hd] = pd;
            }
        }
    }
}

// ---------------------------------------------------------------------------
// Kernel 3: degree histogram over dst.
__global__ __launch_bounds__(256) void hist_kernel(
        const int* __restrict__ ei, const int* __restrict__ flag,
        int* __restrict__ deg) {
    int e = blockIdx.x * 256 + threadIdx.x;
    if (e >= NE) return;
    int is64 = *flag;
    int dst = is64 ? ei[2 * NE + 2 * e] : ei[NE + e];
    atomicAdd(&deg[dst], 1);
}

// ---------------------------------------------------------------------------
// Kernel 4a/4b/4c: exclusive scan of deg -> offsets.
__global__ __launch_bounds__(256) void scanA_kernel(
        const int* __restrict__ deg, int* __restrict__ pre, int* __restrict__ bsum) {
    __shared__ int sd[256];
    int t = threadIdx.x;
    int i = blockIdx.x * 256 + t;
    int v = (i < NN) ? deg[i] : 0;
    sd[t] = v;
    __syncthreads();
    for (int off = 1; off < 256; off <<= 1) {
        int u = (t >= off) ? sd[t - off] : 0;
        __syncthreads();
        sd[t] += u;
        __syncthreads();
    }
    if (i < NN) pre[i] = sd[t] - v;
    if (t == 255) bsum[blockIdx.x] = sd[255];
}

__global__ __launch_bounds__(512) void scanB_kernel(
        const int* __restrict__ bsum, int* __restrict__ boff) {
    __shared__ int sd[512];
    int t = threadIdx.x;
    int v = (t < NB) ? bsum[t] : 0;
    sd[t] = v;
    __syncthreads();
    for (int off = 1; off < 512; off <<= 1) {
        int u = (t >= off) ? sd[t - off] : 0;
        __syncthreads();
        sd[t] += u;
        __syncthreads();
    }
    if (t < NB) boff[t] = sd[t] - v;
}

__global__ __launch_bounds__(256) void scanC_kernel(
        const int* __restrict__ pre, const int* __restrict__ boff,
        int* __restrict__ offsets) {
    int i = blockIdx.x * 256 + threadIdx.x;
    if (i >= NN) return;
    offsets[i] = pre[i] + boff[blockIdx.x];
}

// ---------------------------------------------------------------------------
// Kernel 5a: bucketed multisplit pass 1. Block = 4096 edges; LDS histogram
// over 391 buckets (dst>>8); one global atomic per (block,bucket) claims a
// contiguous range; writes packed (src | dstLocal<<17) at dense ranks.
__global__ __launch_bounds__(256) void bucket_scatter_kernel(
        const int* __restrict__ ei, const int* __restrict__ flag,
        int* __restrict__ bcur, unsigned* __restrict__ pairs) {
    __shared__ int lhist[NBKT];
    __shared__ int gbase[NBKT];
    int t = threadIdx.x;
    for (int i = t; i < NBKT; i += 256) lhist[i] = 0;
    __syncthreads();
    int is64 = *flag;
    int base = blockIdx.x * 4096;

    unsigned wrd[16];
    int meta[16];
#pragma unroll
    for (int it = 0; it < 16; ++it) {
        int e = base + it * 256 + t;
        if (e < NE) {
            int src = is64 ? ei[2 * e] : ei[e];
            int dst = is64 ? ei[2 * NE + 2 * e] : ei[NE + e];
            int b = dst >> 8;
            int r = atomicAdd(&lhist[b], 1);
            wrd[it] = (unsigned)src | ((unsigned)(dst & 255) << 17);
            meta[it] = b | (r << 9);
        } else {
            meta[it] = -1;
        }
    }
    __syncthreads();
    for (int i = t; i < NBKT; i += 256)
        gbase[i] = lhist[i] ? atomicAdd(&bcur[i], lhist[i]) : 0;
    __syncthreads();
#pragma unroll
    for (int it = 0; it < 16; ++it) {
        if (meta[it] >= 0) {
            int b = meta[it] & 511;
            int r = meta[it] >> 9;
            pairs[(size_t)b * BCAP + gbase[b] + r] = wrd[it];
        }
    }
}

// ---------------------------------------------------------------------------
// Kernel 5b: bucket -> final CSR. One block per bucket; cursors for its 256
// nodes in LDS; scattered writes confined to an L2-resident ~16KB window.
__global__ __launch_bounds__(256) void bucket_to_csr_kernel(
        const int* __restrict__ bcur, const unsigned* __restrict__ pairs,
        const int* __restrict__ offsets, int* __restrict__ csr_src) {
    __shared__ int lcur[256];
    int b = blockIdx.x;
    int t = threadIdx.x;
    int node0 = b << 8;
    if (node0 + t < NN) lcur[t] = offsets[node0 + t];
    __syncthreads();
    int cnt = bcur[b];
    const unsigned* __restrict__ bp = pairs + (size_t)b * BCAP;
    for (int i = t; i < cnt; i += 256) {
        unsigned w = bp[i];
        int src = (int)(w & 0x1FFFFu);
        int dl = (int)(w >> 17);
        int pos = atomicAdd(&lcur[dl], 1);
        csr_src[pos] = src;
    }
}

// ---------------------------------------------------------------------------
// Kernel 6: per-node aggregation. One wave per dst; bf16 h gather;
// register accumulation; self-loop + bias + tanh fused. No atomics.
__global__ __launch_bounds__(256) void gat_aggr_kernel(
        const int* __restrict__ offsets, const int* __restrict__ deg,
        const int* __restrict__ csr_src,
        const float* __restrict__ a_src, const float* __restrict__ a_dst,
        const unsigned* __restrict__ h2, const float* __restrict__ bias,
        float* __restrict__ out) {
    int wid = (blockIdx.x * 256 + threadIdx.x) >> 6;
    int lane = threadIdx.x & 63;
    if (wid >= NN) return;
    int dst = wid;
    int hd = lane >> 4;

    float ad = a_dst[dst * 4 + hd];
    int start = offsets[dst];
    int n = deg[dst];

    float accx = 0.f, accy = 0.f, sw = 0.f;
    int j = 0;
    for (; j + 1 < n; j += 2) {
        int s0 = csr_src[start + j];
        int s1 = csr_src[start + j + 1];
        float as0 = a_src[s0 * 4 + hd];
        float as1 = a_src[s1 * 4 + hd];
        unsigned u0 = h2[(size_t)s0 * 64 + lane];
        unsigned u1 = h2[(size_t)s1 * 64 + lane];
        float e0 = as0 + ad; e0 = (e0 < 0.f) ? NEG_SLOPE * e0 : e0;
        float e1 = as1 + ad; e1 = (e1 < 0.f) ? NEG_SLOPE * e1 : e1;
        float w0 = __expf(e0), w1 = __expf(e1);
        accx += w0 * __uint_as_float(u0 << 16) + w1 * __uint_as_float(u1 << 16);
        accy += w0 * __uint_as_float(u0 & 0xFFFF0000u) + w1 * __uint_as_float(u1 & 0xFFFF0000u);
        sw   += w0 + w1;
    }
    if (j < n) {
        int s0 = csr_src[start + j];
        float as0 = a_src[s0 * 4 + hd];
        unsigned u0 = h2[(size_t)s0 * 64 + lane];
        float e0 = as0 + ad; e0 = (e0 < 0.f) ? NEG_SLOPE * e0 : e0;
        float w0 = __expf(e0);
        accx += w0 * __uint_as_float(u0 << 16);
        accy += w0 * __uint_as_float(u0 & 0xFFFF0000u);
        sw += w0;
    }
    {   // self-loop
        float as = a_src[dst * 4 + hd];
        float e0 = as + ad; e0 = (e0 < 0.f) ? NEG_SLOPE * e0 : e0;
        float w0 = __expf(e0);
        unsigned uv = h2[(size_t)dst * 64 + lane];
        accx += w0 * __uint_as_float(uv << 16);
        accy += w0 * __uint_as_float(uv & 0xFFFF0000u);
        sw += w0;
    }
    float inv = 1.f / (sw + 1e-16f);
    float2 b2 = ((const float2*)bias)[lane];
    float2 o;
    o.x = tanhf(accx * inv + b2.x);
    o.y = tanhf(accy * inv + b2.y);
    ((float2*)out)[(size_t)dst * 64 + lane] = o;
}

// ---------------------------------------------------------------------------
extern "C" void kernel_launch(void* const* d_in, const int* in_sizes, int n_in,
                              void* d_out, int out_size, void* d_ws, size_t ws_size,
                              hipStream_t stream) {
    const float* x       = (const float*)d_in[0];
    const int*   ei      = (const int*)  d_in[1];
    const float* W       = (const float*)d_in[2];
    const float* att_src = (const float*)d_in[3];
    const float* att_dst = (const float*)d_in[4];
    const float* bias    = (const float*)d_in[5];
    float* out = (float*)d_out;

    unsigned short* h_bf = (unsigned short*)d_ws;            // NN*128 bf16
    float* a_src = (float*)(h_bf + (size_t)NN * HC);         // NN*4
    float* a_dst = a_src + (size_t)NN * HEADS;               // NN*4
    short* wt_hi = (short*)(a_dst + (size_t)NN * HEADS);     // 16384
    short* wt_lo = wt_hi + F_IN * HC;                        // 16384
    int* flag    = (int*)(wt_lo + F_IN * HC);
    int* deg     = flag + 4;
    int* bcur    = deg + NN;          // NBKT (memset together with deg)
    int* pre     = bcur + 392;
    int* bsum    = pre + NN;          // 512
    int* boff    = bsum + 512;        // 512
    int* offsets = boff + 512;
    int* csr_src = offsets + NN;      // NE
    unsigned* pairs = (unsigned*)(csr_src + NE);  // NBKT*BCAP (~8 MB)

    hipMemsetAsync(deg, 0, (NN + 392) * sizeof(int), stream);

    hipLaunchKernelGGL(prep_kernel, dim3(64), dim3(256), 0, stream,
                       W, wt_hi, wt_lo, ei, flag);

    hipLaunchKernelGGL(hist_kernel, dim3((NE + 255) / 256), dim3(256), 0, stream,
                       ei, flag, deg);

    hipLaunchKernelGGL(mfma_gemm_kernel, dim3((NN / 16 + 3) / 4), dim3(256), 0, stream,
                       x, wt_hi, wt_lo, att_src, att_dst, h_bf, a_src, a_dst);

    hipLaunchKernelGGL(scanA_kernel, dim3(NB), dim3(256), 0, stream, deg, pre, bsum);
    hipLaunchKernelGGL(scanB_kernel, dim3(1), dim3(512), 0, stream, bsum, boff);
    hipLaunchKernelGGL(scanC_kernel, dim3(NB), dim3(256), 0, stream, pre, boff, offsets);

    hipLaunchKernelGGL(bucket_scatter_kernel, dim3((NE + 4095) / 4096), dim3(256), 0, stream,
                       ei, flag, bcur, pairs);

    hipLaunchKernelGGL(bucket_to_csr_kernel, dim3(NBKT), dim3(256), 0, stream,
                       bcur, pairs, offsets, csr_src);

    hipLaunchKernelGGL(gat_aggr_kernel, dim3((NN * 64 + 255) / 256), dim3(256), 0, stream,
                       offsets, deg, csr_src, a_src, a_dst, (const unsigned*)h_bf, bias, out);
}

// Round 6
// 315.298 us; speedup vs baseline: 6.3357x; 1.2283x over previous
//
#include <hip/hip_runtime.h>
#include <math.h>

#define NN 100000
#define NE 1600000
#define F_IN 128
#define HEADS 4
#define HC 128
#define NEG_SLOPE 0.2f
#define NBKT 391    // buckets of 256 dst nodes: (NN+255)/256
#define BCAP 5120   // bucket capacity (mean 4096, sigma 64 -> +16 sigma)

typedef __attribute__((ext_vector_type(8))) short bf16x8;
typedef __attribute__((ext_vector_type(4))) float f32x4;

static __device__ __forceinline__ short f2bf_rne(float f) {
    unsigned u = __float_as_uint(f);
    unsigned r = (u + 0x7FFFu + ((u >> 16) & 1u)) >> 16;
    return (short)r;
}
static __device__ __forceinline__ float bf2f(short s) {
    return __uint_as_float(((unsigned)(unsigned short)s) << 16);
}

// ---------------------------------------------------------------------------
// Kernel 1: W prep (transpose + bf16 hi/lo split) + int64/int32 detect (blk 0)
// + bcur zero (blks 1,2).
__global__ __launch_bounds__(256) void prep_kernel(
        const float* __restrict__ W, short* __restrict__ wt_hi, short* __restrict__ wt_lo,
        const int* __restrict__ ei, int* __restrict__ flag, int* __restrict__ bcur) {
    if (blockIdx.x == 0 && threadIdx.x < 64) {
        int l = threadIdx.x;
        int v = ei[2 * l + 1];
        for (int off = 1; off < 64; off <<= 1) v |= __shfl_xor(v, off);
        if (l == 0) *flag = (v == 0) ? 1 : 0;   // 1 => int64 layout
    }
    if (blockIdx.x == 1 || blockIdx.x == 2) {
        int z = (blockIdx.x - 1) * 256 + threadIdx.x;
        if (z < NBKT) bcur[z] = 0;
    }
    int i = blockIdx.x * 256 + threadIdx.x;
    if (i >= F_IN * HC) return;
    int k = i >> 7, n = i & 127;
    float f = W[k * HC + n];
    short hb = f2bf_rne(f);
    wt_hi[n * F_IN + k] = hb;
    wt_lo[n * F_IN + k] = f2bf_rne(f - bf2f(hb));
}

// ---------------------------------------------------------------------------
// Kernel 2: h = x @ W via split-bf16 MFMA (fp32-equivalent), h stored as bf16.
// Fused epilogue: a_src/a_dst via 16-lane shuffle reductions.
__global__ __launch_bounds__(256) void mfma_gemm_kernel(
        const float* __restrict__ x, const short* __restrict__ wt_hi,
        const short* __restrict__ wt_lo, const float* __restrict__ att_src,
        const float* __restrict__ att_dst, unsigned short* __restrict__ h_bf,
        float* __restrict__ a_src, float* __restrict__ a_dst) {
    int strip = (blockIdx.x * 256 + threadIdx.x) >> 6;
    int lane = threadIdx.x & 63;
    if (strip >= NN / 16) return;
    int l15 = lane & 15;
    int q = lane >> 4;

    f32x4 acc[8];
#pragma unroll
    for (int nt = 0; nt < 8; ++nt) acc[nt] = (f32x4){0.f, 0.f, 0.f, 0.f};

    const float* xp = x + (size_t)(strip * 16 + l15) * F_IN + q * 8;

#pragma unroll
    for (int ki = 0; ki < 4; ++ki) {
        float4 v0 = *(const float4*)(xp + ki * 32);
        float4 v1 = *(const float4*)(xp + ki * 32 + 4);
        float vv[8] = {v0.x, v0.y, v0.z, v0.w, v1.x, v1.y, v1.z, v1.w};
        bf16x8 a_hi, a_lo;
#pragma unroll
        for (int j = 0; j < 8; ++j) {
            short hb = f2bf_rne(vv[j]);
            a_hi[j] = hb;
            a_lo[j] = f2bf_rne(vv[j] - bf2f(hb));
        }
        int koff = ki * 32 + q * 8;
#pragma unroll
        for (int nt = 0; nt < 8; ++nt) {
            int widx = (nt * 16 + l15) * F_IN + koff;
            bf16x8 b_hi = *(const bf16x8*)(wt_hi + widx);
            bf16x8 b_lo = *(const bf16x8*)(wt_lo + widx);
            acc[nt] = __builtin_amdgcn_mfma_f32_16x16x32_bf16(a_hi, b_hi, acc[nt], 0, 0, 0);
            acc[nt] = __builtin_amdgcn_mfma_f32_16x16x32_bf16(a_lo, b_hi, acc[nt], 0, 0, 0);
            acc[nt] = __builtin_amdgcn_mfma_f32_16x16x32_bf16(a_hi, b_lo, acc[nt], 0, 0, 0);
        }
    }

    int orow = strip * 16 + q * 4;
#pragma unroll
    for (int nt = 0; nt < 8; ++nt)
#pragma unroll
        for (int r = 0; r < 4; ++r)
            h_bf[(size_t)(orow + r) * HC + nt * 16 + l15] =
                (unsigned short)f2bf_rne(acc[nt][r]);

    float as0[4], as1[4], ad0[4], ad1[4];
#pragma unroll
    for (int hd = 0; hd < 4; ++hd) {
        as0[hd] = att_src[hd * 32 + l15];
        as1[hd] = att_src[hd * 32 + 16 + l15];
        ad0[hd] = att_dst[hd * 32 + l15];
        ad1[hd] = att_dst[hd * 32 + 16 + l15];
    }
#pragma unroll
    for (int r = 0; r < 4; ++r) {
#pragma unroll
        for (int hd = 0; hd < 4; ++hd) {
            float ps = acc[2 * hd][r] * as0[hd] + acc[2 * hd + 1][r] * as1[hd];
            float pd = acc[2 * hd][r] * ad0[hd] + acc[2 * hd + 1][r] * ad1[hd];
#pragma unroll
            for (int off = 1; off < 16; off <<= 1) {
                ps += __shfl_xor(ps, off);
                pd += __shfl_xor(pd, off);
            }
            if (l15 == 0) {
                int row = orow + r;
                a_src[row * 4 + hd] = ps;
                a_dst[row * 4 + hd] = pd;
            }
        }
    }
}

// ---------------------------------------------------------------------------
// Kernel 3: bucketed multisplit pass 1. Block = 4096 edges; LDS histogram
// over 391 buckets (dst>>8); one global atomic per (block,bucket); writes
// packed (src | dstLocal<<17) at dense ranks.
__global__ __launch_bounds__(256) void bucket_scatter_kernel(
        const int* __restrict__ ei, const int* __restrict__ flag,
        int* __restrict__ bcur, unsigned* __restrict__ pairs) {
    __shared__ int lhist[NBKT];
    __shared__ int gbase[NBKT];
    int t = threadIdx.x;
    for (int i = t; i < NBKT; i += 256) lhist[i] = 0;
    __syncthreads();
    int is64 = *flag;
    int base = blockIdx.x * 4096;

    unsigned wrd[16];
    int meta[16];
#pragma unroll
    for (int it = 0; it < 16; ++it) {
        int e = base + it * 256 + t;
        if (e < NE) {
            int src = is64 ? ei[2 * e] : ei[e];
            int dst = is64 ? ei[2 * NE + 2 * e] : ei[NE + e];
            int b = dst >> 8;
            int r = atomicAdd(&lhist[b], 1);
            wrd[it] = (unsigned)src | ((unsigned)(dst & 255) << 17);
            meta[it] = b | (r << 9);
        } else {
            meta[it] = -1;
        }
    }
    __syncthreads();
    for (int i = t; i < NBKT; i += 256)
        gbase[i] = lhist[i] ? atomicAdd(&bcur[i], lhist[i]) : 0;
    __syncthreads();
#pragma unroll
    for (int it = 0; it < 16; ++it) {
        if (meta[it] >= 0) {
            int b = meta[it] & 511;
            int r = meta[it] >> 9;
            pairs[(size_t)b * BCAP + gbase[b] + r] = wrd[it];
        }
    }
}

// ---------------------------------------------------------------------------
// Kernel 4: bucket -> CSR + per-edge weights + per-node softmax denominators.
// One block per bucket. Computes its own bucket base (reduce over bcur),
// per-node counts + LDS scan -> deg/offsets, scatters csr_src + bf16x4
// weights, accumulates sum-of-weights in LDS, emits {swinv, selfalpha}.
__global__ __launch_bounds__(256) void bucket_csr_kernel(
        const int* __restrict__ bcur, const unsigned* __restrict__ pairs,
        const float* __restrict__ a_src, const float* __restrict__ a_dst,
        int* __restrict__ deg, int* __restrict__ offsets,
        int* __restrict__ csr_src, unsigned* __restrict__ wal,
        float2* __restrict__ selfdata) {
    __shared__ unsigned lpairs[BCAP];   // 20 KB
    __shared__ int sd[256];
    __shared__ int cnt256[256];
    __shared__ int lcur[256];
    __shared__ float sumw[1024];        // 4 KB

    int b = blockIdx.x;
    int t = threadIdx.x;
    int node = (b << 8) + t;

    // bucket base = sum of bcur[0..b)
    int partial = 0;
    for (int i = t; i < b; i += 256) partial += bcur[i];
    sd[t] = partial;
    __syncthreads();
    for (int off = 128; off > 0; off >>= 1) {
        if (t < off) sd[t] += sd[t + off];
        __syncthreads();
    }
    int bktbase = sd[0];
    __syncthreads();

    cnt256[t] = 0;
    for (int i = t; i < 1024; i += 256) sumw[i] = 0.f;
    __syncthreads();

    int cnt = bcur[b];
    const unsigned* __restrict__ bp = pairs + (size_t)b * BCAP;
    for (int i = t; i < cnt; i += 256) {
        unsigned w = bp[i];
        lpairs[i] = w;
        atomicAdd(&cnt256[w >> 17], 1);
    }
    __syncthreads();

    // exclusive scan of cnt256
    int v = cnt256[t];
    sd[t] = v;
    __syncthreads();
    for (int off = 1; off < 256; off <<= 1) {
        int u = (t >= off) ? sd[t - off] : 0;
        __syncthreads();
        sd[t] += u;
        __syncthreads();
    }
    int myoff = bktbase + sd[t] - v;
    if (node < NN) {
        deg[node] = v;
        offsets[node] = myoff;
    }
    lcur[t] = myoff;
    __syncthreads();

    // pass B: weights + scatter
    for (int i = t; i < cnt; i += 256) {
        unsigned w = lpairs[i];
        int src = (int)(w & 0x1FFFFu);
        int dl = (int)(w >> 17);
        float4 as = ((const float4*)a_src)[src];
        float4 ad = ((const float4*)a_dst)[(b << 8) + dl];
        float e0 = as.x + ad.x; e0 = (e0 < 0.f) ? NEG_SLOPE * e0 : e0;
        float e1 = as.y + ad.y; e1 = (e1 < 0.f) ? NEG_SLOPE * e1 : e1;
        float e2 = as.z + ad.z; e2 = (e2 < 0.f) ? NEG_SLOPE * e2 : e2;
        float e3 = as.w + ad.w; e3 = (e3 < 0.f) ? NEG_SLOPE * e3 : e3;
        float w0 = __expf(e0), w1 = __expf(e1), w2 = __expf(e2), w3 = __expf(e3);
        int pos = atomicAdd(&lcur[dl], 1);
        csr_src[pos] = src;
        unsigned lo = (unsigned)(unsigned short)f2bf_rne(w0) |
                      ((unsigned)(unsigned short)f2bf_rne(w1) << 16);
        unsigned hi = (unsigned)(unsigned short)f2bf_rne(w2) |
                      ((unsigned)(unsigned short)f2bf_rne(w3) << 16);
        ((uint2*)wal)[pos] = make_uint2(lo, hi);
        atomicAdd(&sumw[dl * 4 + 0], w0);
        atomicAdd(&sumw[dl * 4 + 1], w1);
        atomicAdd(&sumw[dl * 4 + 2], w2);
        atomicAdd(&sumw[dl * 4 + 3], w3);
    }
    __syncthreads();

    // finalize: self-loop weight, inverse denominator
    if (node < NN) {
        float4 as = ((const float4*)a_src)[node];
        float4 ad = ((const float4*)a_dst)[node];
        float sf[4];
        float e0 = as.x + ad.x; e0 = (e0 < 0.f) ? NEG_SLOPE * e0 : e0; sf[0] = __expf(e0);
        float e1 = as.y + ad.y; e1 = (e1 < 0.f) ? NEG_SLOPE * e1 : e1; sf[1] = __expf(e1);
        float e2 = as.z + ad.z; e2 = (e2 < 0.f) ? NEG_SLOPE * e2 : e2; sf[2] = __expf(e2);
        float e3 = as.w + ad.w; e3 = (e3 < 0.f) ? NEG_SLOPE * e3 : e3; sf[3] = __expf(e3);
#pragma unroll
        for (int hd = 0; hd < 4; ++hd) {
            float tot = sumw[t * 4 + hd] + sf[hd];
            float inv = 1.f / (tot + 1e-16f);
            selfdata[node * 4 + hd] = make_float2(inv, sf[hd] * inv);
        }
    }
}

// ---------------------------------------------------------------------------
// Kernel 5: per-node aggregation. One wave per dst; scalarized index/weight
// loads (s_load), bf16 h gather, register accumulation. No exp, no divide.
__global__ __launch_bounds__(256) void gat_aggr_kernel(
        const int* __restrict__ offsets, const int* __restrict__ deg,
        const int* __restrict__ csr_src, const unsigned* __restrict__ wal,
        const float2* __restrict__ selfdata,
        const unsigned* __restrict__ h2, const float* __restrict__ bias,
        float* __restrict__ out) {
    int wid = (blockIdx.x * 256 + threadIdx.x) >> 6;
    int dst = __builtin_amdgcn_readfirstlane(wid);   // wave-uniform -> SGPR
    if (dst >= NN) return;
    int lane = threadIdx.x & 63;
    int hd = lane >> 4;
    unsigned hsel2 = (unsigned)(hd & 2);
    unsigned hsel1 = (unsigned)(hd & 1);

    int start = offsets[dst];
    int n = deg[dst];
    float2 sdta = selfdata[dst * 4 + hd];   // {swinv, selfalpha}

    float accx = 0.f, accy = 0.f;
    int j = 0;
    for (; j + 3 < n; j += 4) {
        int base = start + j;
        int s0 = csr_src[base + 0];
        int s1 = csr_src[base + 1];
        int s2 = csr_src[base + 2];
        int s3 = csr_src[base + 3];
        uint2 wv0 = ((const uint2*)wal)[base + 0];
        uint2 wv1 = ((const uint2*)wal)[base + 1];
        uint2 wv2 = ((const uint2*)wal)[base + 2];
        uint2 wv3 = ((const uint2*)wal)[base + 3];
        unsigned u0 = h2[(size_t)s0 * 64 + lane];
        unsigned u1 = h2[(size_t)s1 * 64 + lane];
        unsigned u2 = h2[(size_t)s2 * 64 + lane];
        unsigned u3 = h2[(size_t)s3 * 64 + lane];
        unsigned ws0 = hsel2 ? wv0.y : wv0.x;
        unsigned ws1 = hsel2 ? wv1.y : wv1.x;
        unsigned ws2 = hsel2 ? wv2.y : wv2.x;
        unsigned ws3 = hsel2 ? wv3.y : wv3.x;
        float w0 = __uint_as_float(hsel1 ? (ws0 & 0xFFFF0000u) : (ws0 << 16));
        float w1 = __uint_as_float(hsel1 ? (ws1 & 0xFFFF0000u) : (ws1 << 16));
        float w2 = __uint_as_float(hsel1 ? (ws2 & 0xFFFF0000u) : (ws2 << 16));
        float w3 = __uint_as_float(hsel1 ? (ws3 & 0xFFFF0000u) : (ws3 << 16));
        accx += w0 * __uint_as_float(u0 << 16);
        accy += w0 * __uint_as_float(u0 & 0xFFFF0000u);
        accx += w1 * __uint_as_float(u1 << 16);
        accy += w1 * __uint_as_float(u1 & 0xFFFF0000u);
        accx += w2 * __uint_as_float(u2 << 16);
        accy += w2 * __uint_as_float(u2 & 0xFFFF0000u);
        accx += w3 * __uint_as_float(u3 << 16);
        accy += w3 * __uint_as_float(u3 & 0xFFFF0000u);
    }
    for (; j < n; ++j) {
        int base = start + j;
        int s0 = csr_src[base];
        uint2 wv0 = ((const uint2*)wal)[base];
        unsigned u0 = h2[(size_t)s0 * 64 + lane];
        unsigned ws0 = hsel2 ? wv0.y : wv0.x;
        float w0 = __uint_as_float(hsel1 ? (ws0 & 0xFFFF0000u) : (ws0 << 16));
        accx += w0 * __uint_as_float(u0 << 16);
        accy += w0 * __uint_as_float(u0 & 0xFFFF0000u);
    }

    // self-loop + normalize + bias + tanh
    unsigned us = h2[(size_t)dst * 64 + lane];
    float2 b2 = ((const float2*)bias)[lane];
    float ox = tanhf(accx * sdta.x + sdta.y * __uint_as_float(us << 16) + b2.x);
    float oy = tanhf(accy * sdta.x + sdta.y * __uint_as_float(us & 0xFFFF0000u) + b2.y);
    ((float2*)out)[(size_t)dst * 64 + lane] = make_float2(ox, oy);
}

// ---------------------------------------------------------------------------
extern "C" void kernel_launch(void* const* d_in, const int* in_sizes, int n_in,
                              void* d_out, int out_size, void* d_ws, size_t ws_size,
                              hipStream_t stream) {
    const float* x       = (const float*)d_in[0];
    const int*   ei      = (const int*)  d_in[1];
    const float* W       = (const float*)d_in[2];
    const float* att_src = (const float*)d_in[3];
    const float* att_dst = (const float*)d_in[4];
    const float* bias    = (const float*)d_in[5];
    float* out = (float*)d_out;

    unsigned short* h_bf = (unsigned short*)d_ws;            // NN*128 bf16 (25.6 MB)
    float* a_src = (float*)(h_bf + (size_t)NN * HC);         // NN*4
    float* a_dst = a_src + (size_t)NN * HEADS;               // NN*4
    short* wt_hi = (short*)(a_dst + (size_t)NN * HEADS);     // 16384
    short* wt_lo = wt_hi + F_IN * HC;                        // 16384
    int* flag    = (int*)(wt_lo + F_IN * HC);
    int* bcur    = flag + 4;                 // NBKT
    int* deg     = bcur + NBKT + 1;          // NN
    int* offsets = deg + NN;                 // NN
    int* csr_src = offsets + NN;             // NE (6.4 MB)
    unsigned* wal = (unsigned*)(csr_src + NE);               // NE*2 (12.8 MB)
    float2* selfdata = (float2*)(wal + (size_t)NE * 2);      // NN*4 float2 (3.2 MB)
    unsigned* pairs = (unsigned*)(selfdata + (size_t)NN * HEADS);  // NBKT*BCAP (8 MB)

    hipLaunchKernelGGL(prep_kernel, dim3(64), dim3(256), 0, stream,
                       W, wt_hi, wt_lo, ei, flag, bcur);

    hipLaunchKernelGGL(bucket_scatter_kernel, dim3((NE + 4095) / 4096), dim3(256), 0, stream,
                       ei, flag, bcur, pairs);

    hipLaunchKernelGGL(mfma_gemm_kernel, dim3((NN / 16 + 3) / 4), dim3(256), 0, stream,
                       x, wt_hi, wt_lo, att_src, att_dst, h_bf, a_src, a_dst);

    hipLaunchKernelGGL(bucket_csr_kernel, dim3(NBKT), dim3(256), 0, stream,
                       bcur, pairs, a_src, a_dst, deg, offsets, csr_src, wal, selfdata);

    hipLaunchKernelGGL(gat_aggr_kernel, dim3(NN * 64 / 256), dim3(256), 0, stream,
                       offsets, deg, csr_src, wal, selfdata,
                       (const unsigned*)h_bf, bias, out);
}

// Round 7
// 279.033 us; speedup vs baseline: 7.1592x; 1.1300x over previous
//
#include <hip/hip_runtime.h>
#include <math.h>

#define NN 100000
#define NE 1600000
#define F_IN 128
#define HEADS 4
#define HC 128
#define NEG_SLOPE 0.2f
#define NBKT 391    // buckets of 256 dst nodes: (NN+255)/256
#define BCAP 5120   // bucket capacity (mean 4096, sigma 64 -> +16 sigma)
#define LDK 136     // padded LDS row (bf16): 128 + 8 -> 2-way bank alias (free)

typedef __attribute__((ext_vector_type(8))) short bf16x8;
typedef __attribute__((ext_vector_type(4))) float f32x4;

static __device__ __forceinline__ short f2bf_rne(float f) {
    unsigned u = __float_as_uint(f);
    unsigned r = (u + 0x7FFFu + ((u >> 16) & 1u)) >> 16;
    return (short)r;
}
static __device__ __forceinline__ float bf2f(short s) {
    return __uint_as_float(((unsigned)(unsigned short)s) << 16);
}

// ---------------------------------------------------------------------------
// Kernel 1: W prep (transpose + bf16 hi/lo split) + int64/int32 detect (blk 0)
// + bcur zero (blks 1,2).
__global__ __launch_bounds__(256) void prep_kernel(
        const float* __restrict__ W, short* __restrict__ wt_hi, short* __restrict__ wt_lo,
        const int* __restrict__ ei, int* __restrict__ flag, int* __restrict__ bcur) {
    if (blockIdx.x == 0 && threadIdx.x < 64) {
        int l = threadIdx.x;
        int v = ei[2 * l + 1];
        for (int off = 1; off < 64; off <<= 1) v |= __shfl_xor(v, off);
        if (l == 0) *flag = (v == 0) ? 1 : 0;   // 1 => int64 layout
    }
    if (blockIdx.x == 1 || blockIdx.x == 2) {
        int z = (blockIdx.x - 1) * 256 + threadIdx.x;
        if (z < NBKT) bcur[z] = 0;
    }
    int i = blockIdx.x * 256 + threadIdx.x;
    if (i >= F_IN * HC) return;
    int k = i >> 7, n = i & 127;
    float f = W[k * HC + n];
    short hb = f2bf_rne(f);
    wt_hi[n * F_IN + k] = hb;
    wt_lo[n * F_IN + k] = f2bf_rne(f - bf2f(hb));
}

// ---------------------------------------------------------------------------
// Kernel 2: h = x @ W via split-bf16 MFMA, W-half staged in LDS.
// Block = 4 waves = 64 rows x 64 cols (half-N). blockIdx: bit0 = N-half,
// rest = row-block. LDS rows padded to 136 bf16 -> 2-way bank alias (free).
__global__ __launch_bounds__(256) void mfma_gemm_kernel(
        const float* __restrict__ x, const short* __restrict__ wt_hi,
        const short* __restrict__ wt_lo, const float* __restrict__ att_src,
        const float* __restrict__ att_dst, unsigned short* __restrict__ h_bf,
        float* __restrict__ a_src, float* __restrict__ a_dst) {
    __shared__ short lw_hi[64 * LDK];   // 17 KB
    __shared__ short lw_lo[64 * LDK];   // 17 KB
    int t = threadIdx.x;
    int nh = blockIdx.x & 1;            // column half (0: cols 0-63, 1: 64-127)
    int blk = blockIdx.x >> 1;          // row block (64 rows)

    // stage W half: 2 x 16 KB, 16B chunks; chunk c -> row c/16, cols (c%16)*8
    for (int c = t; c < 1024; c += 256) {
        int n = c >> 4;
        int kk = (c & 15) * 8;
        bf16x8 vh = *(const bf16x8*)(wt_hi + (nh * 64 + n) * F_IN + kk);
        bf16x8 vl = *(const bf16x8*)(wt_lo + (nh * 64 + n) * F_IN + kk);
        *(bf16x8*)(lw_hi + n * LDK + kk) = vh;
        *(bf16x8*)(lw_lo + n * LDK + kk) = vl;
    }
    __syncthreads();

    int strip = blk * 4 + (t >> 6);
    if (strip >= NN / 16) return;
    int lane = t & 63;
    int l15 = lane & 15;
    int q = lane >> 4;

    f32x4 acc[4];
#pragma unroll
    for (int nt = 0; nt < 4; ++nt) acc[nt] = (f32x4){0.f, 0.f, 0.f, 0.f};

    const float* xp = x + (size_t)(strip * 16 + l15) * F_IN + q * 8;

#pragma unroll
    for (int ki = 0; ki < 4; ++ki) {
        float4 v0 = *(const float4*)(xp + ki * 32);
        float4 v1 = *(const float4*)(xp + ki * 32 + 4);
        float vv[8] = {v0.x, v0.y, v0.z, v0.w, v1.x, v1.y, v1.z, v1.w};
        bf16x8 a_hi, a_lo;
#pragma unroll
        for (int j = 0; j < 8; ++j) {
            short hb = f2bf_rne(vv[j]);
            a_hi[j] = hb;
            a_lo[j] = f2bf_rne(vv[j] - bf2f(hb));
        }
        int koff = ki * 32 + q * 8;
#pragma unroll
        for (int nt = 0; nt < 4; ++nt) {
            int lidx = (nt * 16 + l15) * LDK + koff;
            bf16x8 b_hi = *(const bf16x8*)(lw_hi + lidx);
            bf16x8 b_lo = *(const bf16x8*)(lw_lo + lidx);
            acc[nt] = __builtin_amdgcn_mfma_f32_16x16x32_bf16(a_hi, b_hi, acc[nt], 0, 0, 0);
            acc[nt] = __builtin_amdgcn_mfma_f32_16x16x32_bf16(a_lo, b_hi, acc[nt], 0, 0, 0);
            acc[nt] = __builtin_amdgcn_mfma_f32_16x16x32_bf16(a_hi, b_lo, acc[nt], 0, 0, 0);
        }
    }

    int orow = strip * 16 + q * 4;
    int cbase = nh * 64;
#pragma unroll
    for (int nt = 0; nt < 4; ++nt)
#pragma unroll
        for (int r = 0; r < 4; ++r)
            h_bf[(size_t)(orow + r) * HC + cbase + nt * 16 + l15] =
                (unsigned short)f2bf_rne(acc[nt][r]);

    // attention dots: this half covers heads {2nh, 2nh+1}; local head hl=nt>>1
#pragma unroll
    for (int hl = 0; hl < 2; ++hl) {
        int hd = nh * 2 + hl;
        float as0 = att_src[hd * 32 + l15];
        float as1 = att_src[hd * 32 + 16 + l15];
        float ad0 = att_dst[hd * 32 + l15];
        float ad1 = att_dst[hd * 32 + 16 + l15];
#pragma unroll
        for (int r = 0; r < 4; ++r) {
            float ps = acc[2 * hl][r] * as0 + acc[2 * hl + 1][r] * as1;
            float pd = acc[2 * hl][r] * ad0 + acc[2 * hl + 1][r] * ad1;
#pragma unroll
            for (int off = 1; off < 16; off <<= 1) {
                ps += __shfl_xor(ps, off);
                pd += __shfl_xor(pd, off);
            }
            if (l15 == 0) {
                int row = orow + r;
                a_src[row * 4 + hd] = ps;
                a_dst[row * 4 + hd] = pd;
            }
        }
    }
}

// ---------------------------------------------------------------------------
// Kernel 3: bucketed multisplit pass 1.
__global__ __launch_bounds__(256) void bucket_scatter_kernel(
        const int* __restrict__ ei, const int* __restrict__ flag,
        int* __restrict__ bcur, unsigned* __restrict__ pairs) {
    __shared__ int lhist[NBKT];
    __shared__ int gbase[NBKT];
    int t = threadIdx.x;
    for (int i = t; i < NBKT; i += 256) lhist[i] = 0;
    __syncthreads();
    int is64 = *flag;
    int base = blockIdx.x * 4096;

    unsigned wrd[16];
    int meta[16];
#pragma unroll
    for (int it = 0; it < 16; ++it) {
        int e = base + it * 256 + t;
        if (e < NE) {
            int src = is64 ? ei[2 * e] : ei[e];
            int dst = is64 ? ei[2 * NE + 2 * e] : ei[NE + e];
            int b = dst >> 8;
            int r = atomicAdd(&lhist[b], 1);
            wrd[it] = (unsigned)src | ((unsigned)(dst & 255) << 17);
            meta[it] = b | (r << 9);
        } else {
            meta[it] = -1;
        }
    }
    __syncthreads();
    for (int i = t; i < NBKT; i += 256)
        gbase[i] = lhist[i] ? atomicAdd(&bcur[i], lhist[i]) : 0;
    __syncthreads();
#pragma unroll
    for (int it = 0; it < 16; ++it) {
        if (meta[it] >= 0) {
            int b = meta[it] & 511;
            int r = meta[it] >> 9;
            pairs[(size_t)b * BCAP + gbase[b] + r] = wrd[it];
        }
    }
}

// ---------------------------------------------------------------------------
// Kernel 4: bucket -> CSR + per-edge weights + per-node softmax denominators.
__global__ __launch_bounds__(256) void bucket_csr_kernel(
        const int* __restrict__ bcur, const unsigned* __restrict__ pairs,
        const float* __restrict__ a_src, const float* __restrict__ a_dst,
        int* __restrict__ deg, int* __restrict__ offsets,
        int* __restrict__ csr_src, unsigned* __restrict__ wal,
        float2* __restrict__ selfdata) {
    __shared__ unsigned lpairs[BCAP];   // 20 KB
    __shared__ int sd[256];
    __shared__ int cnt256[256];
    __shared__ int lcur[256];
    __shared__ float sumw[1024];        // 4 KB

    int b = blockIdx.x;
    int t = threadIdx.x;
    int node = (b << 8) + t;

    int partial = 0;
    for (int i = t; i < b; i += 256) partial += bcur[i];
    sd[t] = partial;
    __syncthreads();
    for (int off = 128; off > 0; off >>= 1) {
        if (t < off) sd[t] += sd[t + off];
        __syncthreads();
    }
    int bktbase = sd[0];
    __syncthreads();

    cnt256[t] = 0;
    for (int i = t; i < 1024; i += 256) sumw[i] = 0.f;
    __syncthreads();

    int cnt = bcur[b];
    const unsigned* __restrict__ bp = pairs + (size_t)b * BCAP;
    for (int i = t; i < cnt; i += 256) {
        unsigned w = bp[i];
        lpairs[i] = w;
        atomicAdd(&cnt256[w >> 17], 1);
    }
    __syncthreads();

    int v = cnt256[t];
    sd[t] = v;
    __syncthreads();
    for (int off = 1; off < 256; off <<= 1) {
        int u = (t >= off) ? sd[t - off] : 0;
        __syncthreads();
        sd[t] += u;
        __syncthreads();
    }
    int myoff = bktbase + sd[t] - v;
    if (node < NN) {
        deg[node] = v;
        offsets[node] = myoff;
    }
    lcur[t] = myoff;
    __syncthreads();

    for (int i = t; i < cnt; i += 256) {
        unsigned w = lpairs[i];
        int src = (int)(w & 0x1FFFFu);
        int dl = (int)(w >> 17);
        float4 as = ((const float4*)a_src)[src];
        float4 ad = ((const float4*)a_dst)[(b << 8) + dl];
        float e0 = as.x + ad.x; e0 = (e0 < 0.f) ? NEG_SLOPE * e0 : e0;
        float e1 = as.y + ad.y; e1 = (e1 < 0.f) ? NEG_SLOPE * e1 : e1;
        float e2 = as.z + ad.z; e2 = (e2 < 0.f) ? NEG_SLOPE * e2 : e2;
        float e3 = as.w + ad.w; e3 = (e3 < 0.f) ? NEG_SLOPE * e3 : e3;
        float w0 = __expf(e0), w1 = __expf(e1), w2 = __expf(e2), w3 = __expf(e3);
        int pos = atomicAdd(&lcur[dl], 1);
        csr_src[pos] = src;
        unsigned lo = (unsigned)(unsigned short)f2bf_rne(w0) |
                      ((unsigned)(unsigned short)f2bf_rne(w1) << 16);
        unsigned hi = (unsigned)(unsigned short)f2bf_rne(w2) |
                      ((unsigned)(unsigned short)f2bf_rne(w3) << 16);
        ((uint2*)wal)[pos] = make_uint2(lo, hi);
        atomicAdd(&sumw[dl * 4 + 0], w0);
        atomicAdd(&sumw[dl * 4 + 1], w1);
        atomicAdd(&sumw[dl * 4 + 2], w2);
        atomicAdd(&sumw[dl * 4 + 3], w3);
    }
    __syncthreads();

    if (node < NN) {
        float4 as = ((const float4*)a_src)[node];
        float4 ad = ((const float4*)a_dst)[node];
        float sf[4];
        float e0 = as.x + ad.x; e0 = (e0 < 0.f) ? NEG_SLOPE * e0 : e0; sf[0] = __expf(e0);
        float e1 = as.y + ad.y; e1 = (e1 < 0.f) ? NEG_SLOPE * e1 : e1; sf[1] = __expf(e1);
        float e2 = as.z + ad.z; e2 = (e2 < 0.f) ? NEG_SLOPE * e2 : e2; sf[2] = __expf(e2);
        float e3 = as.w + ad.w; e3 = (e3 < 0.f) ? NEG_SLOPE * e3 : e3; sf[3] = __expf(e3);
#pragma unroll
        for (int hd = 0; hd < 4; ++hd) {
            float tot = sumw[t * 4 + hd] + sf[hd];
            float inv = 1.f / (tot + 1e-16f);
            selfdata[node * 4 + hd] = make_float2(inv, sf[hd] * inv);
        }
    }
}

// ---------------------------------------------------------------------------
// Kernel 5: per-node aggregation. One wave per dst; scalarized metadata,
// bf16 h gather, register accumulation. No exp, no divide.
__global__ __launch_bounds__(256) void gat_aggr_kernel(
        const int* __restrict__ offsets, const int* __restrict__ deg,
        const int* __restrict__ csr_src, const unsigned* __restrict__ wal,
        const float2* __restrict__ selfdata,
        const unsigned* __restrict__ h2, const float* __restrict__ bias,
        float* __restrict__ out) {
    int wid = (blockIdx.x * 256 + threadIdx.x) >> 6;
    int dst = __builtin_amdgcn_readfirstlane(wid);
    if (dst >= NN) return;
    int lane = threadIdx.x & 63;
    int hd = lane >> 4;
    unsigned hsel2 = (unsigned)(hd & 2);
    unsigned hsel1 = (unsigned)(hd & 1);

    int start = offsets[dst];
    int n = deg[dst];
    float2 sdta = selfdata[dst * 4 + hd];

    float accx = 0.f, accy = 0.f;
    int j = 0;
    for (; j + 3 < n; j += 4) {
        int base = start + j;
        int s0 = csr_src[base + 0];
        int s1 = csr_src[base + 1];
        int s2 = csr_src[base + 2];
        int s3 = csr_src[base + 3];
        uint2 wv0 = ((const uint2*)wal)[base + 0];
        uint2 wv1 = ((const uint2*)wal)[base + 1];
        uint2 wv2 = ((const uint2*)wal)[base + 2];
        uint2 wv3 = ((const uint2*)wal)[base + 3];
        unsigned u0 = h2[(size_t)s0 * 64 + lane];
        unsigned u1 = h2[(size_t)s1 * 64 + lane];
        unsigned u2 = h2[(size_t)s2 * 64 + lane];
        unsigned u3 = h2[(size_t)s3 * 64 + lane];
        unsigned ws0 = hsel2 ? wv0.y : wv0.x;
        unsigned ws1 = hsel2 ? wv1.y : wv1.x;
        unsigned ws2 = hsel2 ? wv2.y : wv2.x;
        unsigned ws3 = hsel2 ? wv3.y : wv3.x;
        float w0 = __uint_as_float(hsel1 ? (ws0 & 0xFFFF0000u) : (ws0 << 16));
        float w1 = __uint_as_float(hsel1 ? (ws1 & 0xFFFF0000u) : (ws1 << 16));
        float w2 = __uint_as_float(hsel1 ? (ws2 & 0xFFFF0000u) : (ws2 << 16));
        float w3 = __uint_as_float(hsel1 ? (ws3 & 0xFFFF0000u) : (ws3 << 16));
        accx += w0 * __uint_as_float(u0 << 16);
        accy += w0 * __uint_as_float(u0 & 0xFFFF0000u);
        accx += w1 * __uint_as_float(u1 << 16);
        accy += w1 * __uint_as_float(u1 & 0xFFFF0000u);
        accx += w2 * __uint_as_float(u2 << 16);
        accy += w2 * __uint_as_float(u2 & 0xFFFF0000u);
        accx += w3 * __uint_as_float(u3 << 16);
        accy += w3 * __uint_as_float(u3 & 0xFFFF0000u);
    }
    for (; j < n; ++j) {
        int base = start + j;
        int s0 = csr_src[base];
        uint2 wv0 = ((const uint2*)wal)[base];
        unsigned u0 = h2[(size_t)s0 * 64 + lane];
        unsigned ws0 = hsel2 ? wv0.y : wv0.x;
        float w0 = __uint_as_float(hsel1 ? (ws0 & 0xFFFF0000u) : (ws0 << 16));
        accx += w0 * __uint_as_float(u0 << 16);
        accy += w0 * __uint_as_float(u0 & 0xFFFF0000u);
    }

    unsigned us = h2[(size_t)dst * 64 + lane];
    float2 b2 = ((const float2*)bias)[lane];
    float ox = tanhf(accx * sdta.x + sdta.y * __uint_as_float(us << 16) + b2.x);
    float oy = tanhf(accy * sdta.x + sdta.y * __uint_as_float(us & 0xFFFF0000u) + b2.y);
    ((float2*)out)[(size_t)dst * 64 + lane] = make_float2(ox, oy);
}

// ---------------------------------------------------------------------------
extern "C" void kernel_launch(void* const* d_in, const int* in_sizes, int n_in,
                              void* d_out, int out_size, void* d_ws, size_t ws_size,
                              hipStream_t stream) {
    const float* x       = (const float*)d_in[0];
    const int*   ei      = (const int*)  d_in[1];
    const float* W       = (const float*)d_in[2];
    const float* att_src = (const float*)d_in[3];
    const float* att_dst = (const float*)d_in[4];
    const float* bias    = (const float*)d_in[5];
    float* out = (float*)d_out;

    unsigned short* h_bf = (unsigned short*)d_ws;            // NN*128 bf16 (25.6 MB)
    float* a_src = (float*)(h_bf + (size_t)NN * HC);         // NN*4
    float* a_dst = a_src + (size_t)NN * HEADS;               // NN*4
    short* wt_hi = (short*)(a_dst + (size_t)NN * HEADS);     // 16384
    short* wt_lo = wt_hi + F_IN * HC;                        // 16384
    int* flag    = (int*)(wt_lo + F_IN * HC);
    int* bcur    = flag + 4;                 // NBKT
    int* deg     = bcur + NBKT + 1;          // NN
    int* offsets = deg + NN;                 // NN
    int* csr_src = offsets + NN;             // NE (6.4 MB)
    unsigned* wal = (unsigned*)(csr_src + NE);               // NE*2 (12.8 MB)
    float2* selfdata = (float2*)(wal + (size_t)NE * 2);      // NN*4 float2 (3.2 MB)
    unsigned* pairs = (unsigned*)(selfdata + (size_t)NN * HEADS);  // NBKT*BCAP (8 MB)

    hipLaunchKernelGGL(prep_kernel, dim3(64), dim3(256), 0, stream,
                       W, wt_hi, wt_lo, ei, flag, bcur);

    hipLaunchKernelGGL(bucket_scatter_kernel, dim3((NE + 4095) / 4096), dim3(256), 0, stream,
                       ei, flag, bcur, pairs);

    // 2 column-halves x 1563 row-blocks (64 rows each, last partial)
    hipLaunchKernelGGL(mfma_gemm_kernel, dim3(1563 * 2), dim3(256), 0, stream,
                       x, wt_hi, wt_lo, att_src, att_dst, h_bf, a_src, a_dst);

    hipLaunchKernelGGL(bucket_csr_kernel, dim3(NBKT), dim3(256), 0, stream,
                       bcur, pairs, a_src, a_dst, deg, offsets, csr_src, wal, selfdata);

    hipLaunchKernelGGL(gat_aggr_kernel, dim3(NN * 64 / 256), dim3(256), 0, stream,
                       offsets, deg, csr_src, wal, selfdata,
                       (const unsigned*)h_bf, bias, out);
}